// Round 1
// baseline (2224.126 us; speedup 1.0000x reference)
//
#include <hip/hip_runtime.h>
#include <math.h>

#define DM   1024
#define NH   16
#define DH   64
#define SEQ  2048
#define BATCH 4

// ---------------- fp32 tiled GEMM: C[M,N] = A[M,K] @ B[K,N] (+bias) --------
// 64x64 tile, BK=16, 256 threads, 4x4 accumulator per thread.
__global__ __launch_bounds__(256) void gemm_f32(
    const float* __restrict__ A, const float* __restrict__ B,
    const float* __restrict__ bias, float* __restrict__ C,
    int M, int N, int K)
{
    __shared__ float As[16][64];      // [k][m]  row = 256B, 16B-aligned
    __shared__ float Bs[16][68];      // [k][n]  row = 272B = 17*16B, aligned
    const int tid = threadIdx.x;
    const int tx = tid & 15, ty = tid >> 4;
    const int bm = blockIdx.x * 64, bn = blockIdx.y * 64;

    float acc[4][4] = {};

    for (int k0 = 0; k0 < K; k0 += 16) {
        // A tile: 64 rows x 16 k.  lanes 0..15 read 16 consecutive floats.
        #pragma unroll
        for (int i = tid; i < 64 * 16; i += 256) {
            int m = i >> 4, k = i & 15;
            As[k][m] = A[(size_t)(bm + m) * K + k0 + k];
        }
        // B tile: 16 rows x 64 n. 64 consecutive floats per row.
        #pragma unroll
        for (int i = tid; i < 16 * 64; i += 256) {
            int k = i >> 6, n = i & 63;
            Bs[k][n] = B[(size_t)(k0 + k) * N + bn + n];
        }
        __syncthreads();
        #pragma unroll
        for (int k = 0; k < 16; ++k) {
            float a[4], b[4];
            *reinterpret_cast<float4*>(a) = *reinterpret_cast<const float4*>(&As[k][ty * 4]);
            *reinterpret_cast<float4*>(b) = *reinterpret_cast<const float4*>(&Bs[k][tx * 4]);
            #pragma unroll
            for (int i = 0; i < 4; ++i)
                #pragma unroll
                for (int j = 0; j < 4; ++j)
                    acc[i][j] = fmaf(a[i], b[j], acc[i][j]);
        }
        __syncthreads();
    }

    #pragma unroll
    for (int i = 0; i < 4; ++i) {
        int r = bm + ty * 4 + i;
        int c = bn + tx * 4;
        float4 o;
        o.x = acc[i][0]; o.y = acc[i][1]; o.z = acc[i][2]; o.w = acc[i][3];
        if (bias) {
            o.x += bias[c + 0]; o.y += bias[c + 1];
            o.z += bias[c + 2]; o.w += bias[c + 3];
        }
        *reinterpret_cast<float4*>(C + (size_t)r * N + c) = o;
    }
}

// ---------------- flash attention fp32 ------------------------------------
// grid: (SEQ/64, NH, BATCH), block 256.
// qkv layout: [B*SEQ][3072]; Q cols 0..1023, K cols 1024..2047, V cols 2048..3071,
// head h occupies 64 cols at offset h*64 within each section.
// out: [B*SEQ][1024] attention output (pre out-proj), col = h*64 + d.
__global__ __launch_bounds__(256) void flash_attn(
    const float* __restrict__ qkv, float* __restrict__ out)
{
    const int qt = blockIdx.x;
    const int h  = blockIdx.y;
    const int b  = blockIdx.z;
    const int tid = threadIdx.x;
    const int tx = tid & 15, ty = tid >> 4;

    __shared__ float Qs[DH][68];     // Q^T (scaled): Qs[d][r]
    __shared__ float Ks[DH][68];     // K^T:          Ks[d][c]
    __shared__ float Vs[64][68];     // V:            Vs[j][c]
    __shared__ float Ps[64][68];     // P:            Ps[r][j]

    const size_t base = (size_t)b * SEQ * 3072;
    const float scale = 0.125f;       // 1/sqrt(64)

    // ---- load Q tile, transposed + scaled ----
    {
        const float* qp = qkv + base + (size_t)qt * 64 * 3072 + h * DH;
        #pragma unroll
        for (int idx = tid; idx < 64 * 16; idx += 256) {
            int r = idx >> 4, c4 = (idx & 15) * 4;
            float4 v = *reinterpret_cast<const float4*>(qp + (size_t)r * 3072 + c4);
            Qs[c4 + 0][r] = v.x * scale;
            Qs[c4 + 1][r] = v.y * scale;
            Qs[c4 + 2][r] = v.z * scale;
            Qs[c4 + 3][r] = v.w * scale;
        }
    }

    float m_[4], l_[4], acc[4][4];
    #pragma unroll
    for (int i = 0; i < 4; ++i) {
        m_[i] = -1e30f; l_[i] = 0.f;
        #pragma unroll
        for (int j = 0; j < 4; ++j) acc[i][j] = 0.f;
    }

    const float* kbase = qkv + base + 1024 + h * DH;
    const float* vbase = qkv + base + 2048 + h * DH;

    for (int kt = 0; kt < SEQ / 64; ++kt) {
        __syncthreads();   // prev iteration's PV reads done before overwrite
        const float* kp = kbase + (size_t)kt * 64 * 3072;
        const float* vp = vbase + (size_t)kt * 64 * 3072;
        #pragma unroll
        for (int idx = tid; idx < 64 * 16; idx += 256) {
            int r = idx >> 4, c4 = (idx & 15) * 4;
            float4 kv = *reinterpret_cast<const float4*>(kp + (size_t)r * 3072 + c4);
            Ks[c4 + 0][r] = kv.x; Ks[c4 + 1][r] = kv.y;
            Ks[c4 + 2][r] = kv.z; Ks[c4 + 3][r] = kv.w;
            float4 vv = *reinterpret_cast<const float4*>(vp + (size_t)r * 3072 + c4);
            *reinterpret_cast<float4*>(&Vs[r][c4]) = vv;
        }
        __syncthreads();

        // ---- S = (Q*scale) @ K^T : per-thread 4x4 ----
        float s[4][4] = {};
        #pragma unroll 4
        for (int d = 0; d < DH; ++d) {
            float a[4], kk[4];
            *reinterpret_cast<float4*>(a)  = *reinterpret_cast<const float4*>(&Qs[d][ty * 4]);
            *reinterpret_cast<float4*>(kk) = *reinterpret_cast<const float4*>(&Ks[d][tx * 4]);
            #pragma unroll
            for (int i = 0; i < 4; ++i)
                #pragma unroll
                for (int j = 0; j < 4; ++j)
                    s[i][j] = fmaf(a[i], kk[j], s[i][j]);
        }

        // ---- online softmax (row groups = 16 lanes sharing ty) ----
        #pragma unroll
        for (int i = 0; i < 4; ++i) {
            float mx = fmaxf(fmaxf(s[i][0], s[i][1]), fmaxf(s[i][2], s[i][3]));
            #pragma unroll
            for (int off = 1; off < 16; off <<= 1)
                mx = fmaxf(mx, __shfl_xor(mx, off));
            float mnew  = fmaxf(m_[i], mx);
            float alpha = __expf(m_[i] - mnew);
            float p[4], rs = 0.f;
            #pragma unroll
            for (int j = 0; j < 4; ++j) { p[j] = __expf(s[i][j] - mnew); rs += p[j]; }
            #pragma unroll
            for (int off = 1; off < 16; off <<= 1)
                rs += __shfl_xor(rs, off);
            l_[i] = l_[i] * alpha + rs;
            m_[i] = mnew;
            #pragma unroll
            for (int j = 0; j < 4; ++j) acc[i][j] *= alpha;
            float4 pv; pv.x = p[0]; pv.y = p[1]; pv.z = p[2]; pv.w = p[3];
            *reinterpret_cast<float4*>(&Ps[ty * 4 + i][tx * 4]) = pv;
        }
        __syncthreads();

        // ---- O += P @ V ----
        #pragma unroll 4
        for (int j0 = 0; j0 < 64; j0 += 4) {
            float pr[4][4];
            #pragma unroll
            for (int i = 0; i < 4; ++i)
                *reinterpret_cast<float4*>(pr[i]) =
                    *reinterpret_cast<const float4*>(&Ps[ty * 4 + i][j0]);
            #pragma unroll
            for (int jj = 0; jj < 4; ++jj) {
                float vv[4];
                *reinterpret_cast<float4*>(vv) =
                    *reinterpret_cast<const float4*>(&Vs[j0 + jj][tx * 4]);
                #pragma unroll
                for (int i = 0; i < 4; ++i)
                    #pragma unroll
                    for (int c = 0; c < 4; ++c)
                        acc[i][c] = fmaf(pr[i][jj], vv[c], acc[i][c]);
            }
        }
    }

    // ---- epilogue: O / l -> out[b*SEQ + row][h*64 + d] ----
    #pragma unroll
    for (int i = 0; i < 4; ++i) {
        float inv = 1.f / l_[i];
        int r = qt * 64 + ty * 4 + i;
        float4 o;
        o.x = acc[i][0] * inv; o.y = acc[i][1] * inv;
        o.z = acc[i][2] * inv; o.w = acc[i][3] * inv;
        *reinterpret_cast<float4*>(out + ((size_t)(b * SEQ + r)) * DM + h * DH + tx * 4) = o;
    }
}

extern "C" void kernel_launch(void* const* d_in, const int* in_sizes, int n_in,
                              void* d_out, int out_size, void* d_ws, size_t ws_size,
                              hipStream_t stream) {
    const float* x     = (const float*)d_in[0];   // [4,2048,1024]
    const float* w_qkv = (const float*)d_in[1];   // [1024,3072]
    const float* w_out = (const float*)d_in[2];   // [1024,1024]
    const float* b_out = (const float*)d_in[3];   // [1024]
    float* out = (float*)d_out;                   // [4,2048,1024]

    const int M = BATCH * SEQ;                    // 8192
    float* qkv  = (float*)d_ws;                   // M*3072 floats (100.7 MB)
    float* attn = qkv + (size_t)M * 3 * DM;       // M*1024 floats (33.5 MB)

    dim3 blk(256);
    // 1) qkv = x @ w_qkv
    gemm_f32<<<dim3(M / 64, (3 * DM) / 64), blk, 0, stream>>>(
        x, w_qkv, nullptr, qkv, M, 3 * DM, DM);
    // 2) flash attention per (q-tile, head, batch)
    flash_attn<<<dim3(SEQ / 64, NH, BATCH), blk, 0, stream>>>(qkv, attn);
    // 3) out = attn @ w_out + b_out
    gemm_f32<<<dim3(M / 64, DM / 64), blk, 0, stream>>>(
        attn, w_out, b_out, out, M, DM, DM);
}

// Round 2
// 1394.977 us; speedup vs baseline: 1.5944x; 1.5944x over previous
//
#include <hip/hip_runtime.h>
#include <math.h>

#define DM   1024
#define NH   16
#define DH   64
#define SEQ  2048
#define BATCH 4

typedef __attribute__((ext_vector_type(8))) short  short8;
typedef __attribute__((ext_vector_type(4))) float  f32x4;

// ---- fp32 -> bf16 hi/lo split helpers (RNE) -------------------------------
static __device__ __forceinline__ unsigned short f2bf(float f) {
    unsigned u = __float_as_uint(f);
    unsigned r = (u + 0x7fffu + ((u >> 16) & 1u)) >> 16;
    return (unsigned short)r;
}
static __device__ __forceinline__ float bf2f(unsigned short h) {
    return __uint_as_float(((unsigned)h) << 16);
}

// ---- prep: elementwise split fp32 -> (hi, lo) bf16, same layout -----------
__global__ __launch_bounds__(256) void split_hl(
    const float* __restrict__ in, unsigned short* __restrict__ hi,
    unsigned short* __restrict__ lo, int n4)
{
    int i = blockIdx.x * 256 + threadIdx.x;
    if (i >= n4) return;
    float4 v = reinterpret_cast<const float4*>(in)[i];
    ushort4 h, L;
    h.x = f2bf(v.x); L.x = f2bf(v.x - bf2f(h.x));
    h.y = f2bf(v.y); L.y = f2bf(v.y - bf2f(h.y));
    h.z = f2bf(v.z); L.z = f2bf(v.z - bf2f(h.z));
    h.w = f2bf(v.w); L.w = f2bf(v.w - bf2f(h.w));
    reinterpret_cast<ushort4*>(hi)[i] = h;
    reinterpret_cast<ushort4*>(lo)[i] = L;
}

// ---- prep: split + transpose: in[K][N] fp32 -> hiT/loT[N][K] bf16 ---------
__global__ __launch_bounds__(256) void splitT_hl(
    const float* __restrict__ in, unsigned short* __restrict__ hiT,
    unsigned short* __restrict__ loT, int K, int N)
{
    __shared__ float t[32][33];
    const int n0 = blockIdx.x * 32, k0 = blockIdx.y * 32;
    const int tx = threadIdx.x & 31, ty = threadIdx.x >> 5;   // 32 x 8
    #pragma unroll
    for (int r = 0; r < 32; r += 8)
        t[ty + r][tx] = in[(size_t)(k0 + ty + r) * N + n0 + tx];
    __syncthreads();
    #pragma unroll
    for (int r = 0; r < 32; r += 8) {
        float v = t[tx][ty + r];                 // element [k0+tx][n0+ty+r]
        unsigned short h = f2bf(v);
        size_t o = (size_t)(n0 + ty + r) * K + k0 + tx;
        hiT[o] = h;
        loT[o] = f2bf(v - bf2f(h));
    }
}

// ---- split-bf16 3-pass MFMA GEMM: C[M,N] = A @ B^T (+bias) ----------------
// A as (Ah+Al)[M][K] bf16, B as (Bh+Bl)[N][K] bf16 (pre-transposed).
// 128x128 tile, BK=32, 256 threads = 4 waves (2x2), 4x4 16x16 frags/wave.
#define GLD(gp, lp) __builtin_amdgcn_global_load_lds( \
    (const __attribute__((address_space(1))) void*)(gp), \
    (__attribute__((address_space(3))) void*)(lp), 16, 0, 0)

__global__ __launch_bounds__(256) void gemm_bt_3p(
    const unsigned short* __restrict__ Ah, const unsigned short* __restrict__ Al,
    const unsigned short* __restrict__ Bh, const unsigned short* __restrict__ Bl,
    const float* __restrict__ bias, float* __restrict__ C,
    int M, int N, int K)
{
    __shared__ __align__(16) unsigned short sAh[128 * 32];
    __shared__ __align__(16) unsigned short sAl[128 * 32];
    __shared__ __align__(16) unsigned short sBh[128 * 32];
    __shared__ __align__(16) unsigned short sBl[128 * 32];

    const int tid = threadIdx.x;
    const int l = tid & 63, w = tid >> 6;
    const int wr = w >> 1, wc = w & 1;
    const int bm = blockIdx.x * 128, bn = blockIdx.y * 128;

    // staging: wave w stages rows [w*32, w*32+32); lane l -> 16B chunk
    const int srow = w * 32 + (l >> 2);          // +16 for second chunk
    const int scol = (l & 3) * 8;                // shorts
    const size_t a0 = (size_t)(bm + srow) * K + scol;
    const size_t a1 = (size_t)(bm + srow + 16) * K + scol;
    const size_t b0 = (size_t)(bn + srow) * K + scol;
    const size_t b1 = (size_t)(bn + srow + 16) * K + scol;
    unsigned short* lA = sAh + w * 1024;         // generic; per-array below

    const int fr = l & 15;                       // frag row/col within 16
    const int fk = (l >> 4) * 8;                 // frag k offset (shorts)

    f32x4 acc[4][4];
    #pragma unroll
    for (int i = 0; i < 4; ++i)
        #pragma unroll
        for (int j = 0; j < 4; ++j)
            acc[i][j] = (f32x4){0.f, 0.f, 0.f, 0.f};

    for (int k0 = 0; k0 < K; k0 += 32) {
        __syncthreads();
        GLD(Ah + a0 + k0, sAh + w * 1024);
        GLD(Ah + a1 + k0, sAh + w * 1024 + 512);
        GLD(Al + a0 + k0, sAl + w * 1024);
        GLD(Al + a1 + k0, sAl + w * 1024 + 512);
        GLD(Bh + b0 + k0, sBh + w * 1024);
        GLD(Bh + b1 + k0, sBh + w * 1024 + 512);
        GLD(Bl + b0 + k0, sBl + w * 1024);
        GLD(Bl + b1 + k0, sBl + w * 1024 + 512);
        __syncthreads();

        short8 vah[4], val[4], vbh[4], vbl[4];
        #pragma unroll
        for (int i = 0; i < 4; ++i) {
            int ar = (wr * 64 + i * 16 + fr) * 32 + fk;
            int br = (wc * 64 + i * 16 + fr) * 32 + fk;
            vah[i] = *reinterpret_cast<const short8*>(&sAh[ar]);
            val[i] = *reinterpret_cast<const short8*>(&sAl[ar]);
            vbh[i] = *reinterpret_cast<const short8*>(&sBh[br]);
            vbl[i] = *reinterpret_cast<const short8*>(&sBl[br]);
        }
        #pragma unroll
        for (int i = 0; i < 4; ++i)
            #pragma unroll
            for (int j = 0; j < 4; ++j) {
                acc[i][j] = __builtin_amdgcn_mfma_f32_16x16x32_bf16(vah[i], vbh[j], acc[i][j], 0, 0, 0);
                acc[i][j] = __builtin_amdgcn_mfma_f32_16x16x32_bf16(vah[i], vbl[j], acc[i][j], 0, 0, 0);
                acc[i][j] = __builtin_amdgcn_mfma_f32_16x16x32_bf16(val[i], vbh[j], acc[i][j], 0, 0, 0);
            }
    }

    // C/D layout: col = lane&15, row = (lane>>4)*4 + reg
    #pragma unroll
    for (int i = 0; i < 4; ++i) {
        #pragma unroll
        for (int j = 0; j < 4; ++j) {
            int row = bm + wr * 64 + i * 16 + (l >> 4) * 4;
            int col = bn + wc * 64 + j * 16 + fr;
            float bb = bias ? bias[col] : 0.f;
            #pragma unroll
            for (int r = 0; r < 4; ++r)
                C[(size_t)(row + r) * N + col] = acc[i][j][r] + bb;
        }
    }
}

// ---------------- flash attention fp32 (unchanged core) --------------------
__global__ __launch_bounds__(256) void flash_attn(
    const float* __restrict__ qkv,
    unsigned short* __restrict__ out_hi, unsigned short* __restrict__ out_lo)
{
    const int qt = blockIdx.x;
    const int h  = blockIdx.y;
    const int b  = blockIdx.z;
    const int tid = threadIdx.x;
    const int tx = tid & 15, ty = tid >> 4;

    __shared__ float Qs[DH][68];
    __shared__ float Ks[DH][68];
    __shared__ float Vs[64][68];
    __shared__ float Ps[64][68];

    const size_t base = (size_t)b * SEQ * 3072;
    const float scale = 0.125f;

    {
        const float* qp = qkv + base + (size_t)qt * 64 * 3072 + h * DH;
        #pragma unroll
        for (int idx = tid; idx < 64 * 16; idx += 256) {
            int r = idx >> 4, c4 = (idx & 15) * 4;
            float4 v = *reinterpret_cast<const float4*>(qp + (size_t)r * 3072 + c4);
            Qs[c4 + 0][r] = v.x * scale;
            Qs[c4 + 1][r] = v.y * scale;
            Qs[c4 + 2][r] = v.z * scale;
            Qs[c4 + 3][r] = v.w * scale;
        }
    }

    float m_[4], l_[4], acc[4][4];
    #pragma unroll
    for (int i = 0; i < 4; ++i) {
        m_[i] = -1e30f; l_[i] = 0.f;
        #pragma unroll
        for (int j = 0; j < 4; ++j) acc[i][j] = 0.f;
    }

    const float* kbase = qkv + base + 1024 + h * DH;
    const float* vbase = qkv + base + 2048 + h * DH;

    for (int kt = 0; kt < SEQ / 64; ++kt) {
        __syncthreads();
        const float* kp = kbase + (size_t)kt * 64 * 3072;
        const float* vp = vbase + (size_t)kt * 64 * 3072;
        #pragma unroll
        for (int idx = tid; idx < 64 * 16; idx += 256) {
            int r = idx >> 4, c4 = (idx & 15) * 4;
            float4 kv = *reinterpret_cast<const float4*>(kp + (size_t)r * 3072 + c4);
            Ks[c4 + 0][r] = kv.x; Ks[c4 + 1][r] = kv.y;
            Ks[c4 + 2][r] = kv.z; Ks[c4 + 3][r] = kv.w;
            float4 vv = *reinterpret_cast<const float4*>(vp + (size_t)r * 3072 + c4);
            *reinterpret_cast<float4*>(&Vs[r][c4]) = vv;
        }
        __syncthreads();

        float s[4][4] = {};
        #pragma unroll 4
        for (int d = 0; d < DH; ++d) {
            float a[4], kk[4];
            *reinterpret_cast<float4*>(a)  = *reinterpret_cast<const float4*>(&Qs[d][ty * 4]);
            *reinterpret_cast<float4*>(kk) = *reinterpret_cast<const float4*>(&Ks[d][tx * 4]);
            #pragma unroll
            for (int i = 0; i < 4; ++i)
                #pragma unroll
                for (int j = 0; j < 4; ++j)
                    s[i][j] = fmaf(a[i], kk[j], s[i][j]);
        }

        #pragma unroll
        for (int i = 0; i < 4; ++i) {
            float mx = fmaxf(fmaxf(s[i][0], s[i][1]), fmaxf(s[i][2], s[i][3]));
            #pragma unroll
            for (int off = 1; off < 16; off <<= 1)
                mx = fmaxf(mx, __shfl_xor(mx, off));
            float mnew  = fmaxf(m_[i], mx);
            float alpha = __expf(m_[i] - mnew);
            float p[4], rs = 0.f;
            #pragma unroll
            for (int j = 0; j < 4; ++j) { p[j] = __expf(s[i][j] - mnew); rs += p[j]; }
            #pragma unroll
            for (int off = 1; off < 16; off <<= 1)
                rs += __shfl_xor(rs, off);
            l_[i] = l_[i] * alpha + rs;
            m_[i] = mnew;
            #pragma unroll
            for (int j = 0; j < 4; ++j) acc[i][j] *= alpha;
            float4 pv; pv.x = p[0]; pv.y = p[1]; pv.z = p[2]; pv.w = p[3];
            *reinterpret_cast<float4*>(&Ps[ty * 4 + i][tx * 4]) = pv;
        }
        __syncthreads();

        #pragma unroll 4
        for (int j0 = 0; j0 < 64; j0 += 4) {
            float pr[4][4];
            #pragma unroll
            for (int i = 0; i < 4; ++i)
                *reinterpret_cast<float4*>(pr[i]) =
                    *reinterpret_cast<const float4*>(&Ps[ty * 4 + i][j0]);
            #pragma unroll
            for (int jj = 0; jj < 4; ++jj) {
                float vv[4];
                *reinterpret_cast<float4*>(vv) =
                    *reinterpret_cast<const float4*>(&Vs[j0 + jj][tx * 4]);
                #pragma unroll
                for (int i = 0; i < 4; ++i)
                    #pragma unroll
                    for (int c = 0; c < 4; ++c)
                        acc[i][c] = fmaf(pr[i][jj], vv[c], acc[i][c]);
            }
        }
    }

    // epilogue: O / l -> hi/lo bf16 at out[b*SEQ+row][h*64 + d]
    #pragma unroll
    for (int i = 0; i < 4; ++i) {
        float inv = 1.f / l_[i];
        int r = qt * 64 + ty * 4 + i;
        size_t o = ((size_t)(b * SEQ + r)) * DM + h * DH + tx * 4;
        #pragma unroll
        for (int c = 0; c < 4; ++c) {
            float v = acc[i][c] * inv;
            unsigned short hh = f2bf(v);
            out_hi[o + c] = hh;
            out_lo[o + c] = f2bf(v - bf2f(hh));
        }
    }
}

extern "C" void kernel_launch(void* const* d_in, const int* in_sizes, int n_in,
                              void* d_out, int out_size, void* d_ws, size_t ws_size,
                              hipStream_t stream) {
    const float* x     = (const float*)d_in[0];   // [8192,1024]
    const float* w_qkv = (const float*)d_in[1];   // [1024,3072]
    const float* w_out = (const float*)d_in[2];   // [1024,1024]
    const float* b_out = (const float*)d_in[3];   // [1024]
    float* out = (float*)d_out;                   // [8192,1024]

    const int M = BATCH * SEQ;                    // 8192

    // workspace layout (bytes): total ~184.5 MB
    char* ws = (char*)d_ws;
    float*          qkv   = (float*)ws;                                  ws += (size_t)M * 3072 * 4;   // 100.7 MB
    unsigned short* x_hi  = (unsigned short*)ws;                         ws += (size_t)M * DM * 2;
    unsigned short* x_lo  = (unsigned short*)ws;                         ws += (size_t)M * DM * 2;
    unsigned short* wqT_h = (unsigned short*)ws;                         ws += (size_t)3072 * DM * 2;
    unsigned short* wqT_l = (unsigned short*)ws;                         ws += (size_t)3072 * DM * 2;
    unsigned short* woT_h = (unsigned short*)ws;                         ws += (size_t)DM * DM * 2;
    unsigned short* woT_l = (unsigned short*)ws;                         ws += (size_t)DM * DM * 2;
    unsigned short* at_hi = (unsigned short*)ws;                         ws += (size_t)M * DM * 2;
    unsigned short* at_lo = (unsigned short*)ws;

    dim3 blk(256);

    // prep: split x; split+transpose weights
    split_hl<<<dim3((M * DM / 4 + 255) / 256), blk, 0, stream>>>(x, x_hi, x_lo, M * DM / 4);
    splitT_hl<<<dim3(3072 / 32, DM / 32), blk, 0, stream>>>(w_qkv, wqT_h, wqT_l, DM, 3 * DM);
    splitT_hl<<<dim3(DM / 32, DM / 32), blk, 0, stream>>>(w_out, woT_h, woT_l, DM, DM);

    // 1) qkv = x @ w_qkv  (fp32 out)
    gemm_bt_3p<<<dim3(M / 128, 3 * DM / 128), blk, 0, stream>>>(
        x_hi, x_lo, wqT_h, wqT_l, nullptr, qkv, M, 3 * DM, DM);

    // 2) flash attention -> attn (hi/lo bf16)
    flash_attn<<<dim3(SEQ / 64, NH, BATCH), blk, 0, stream>>>(qkv, at_hi, at_lo);

    // 3) out = attn @ w_out + b_out
    gemm_bt_3p<<<dim3(M / 128, DM / 128), blk, 0, stream>>>(
        at_hi, at_lo, woT_h, woT_l, b_out, out, M, DM, DM);
}

// Round 3
// 760.005 us; speedup vs baseline: 2.9265x; 1.8355x over previous
//
#include <hip/hip_runtime.h>
#include <math.h>

#define DM   1024
#define NH   16
#define DH   64
#define SEQ  2048
#define BATCH 4

typedef __attribute__((ext_vector_type(8))) short  short8;
typedef __attribute__((ext_vector_type(4))) float  f32x4;

// ---- fp32 -> bf16 hi/lo split helpers (RNE) -------------------------------
static __device__ __forceinline__ unsigned short f2bf(float f) {
    unsigned u = __float_as_uint(f);
    unsigned r = (u + 0x7fffu + ((u >> 16) & 1u)) >> 16;
    return (unsigned short)r;
}
static __device__ __forceinline__ float bf2f(unsigned short h) {
    return __uint_as_float(((unsigned)h) << 16);
}

// swizzled byte offset inside a [64 rows][128B] LDS tile (T2-style, G4 rule)
static __device__ __forceinline__ int swz(int row, int cbyte) {
    return row * 128 + (cbyte ^ ((row & 7) << 4));
}

#define GLD(gp, lp) __builtin_amdgcn_global_load_lds( \
    (const __attribute__((address_space(1))) void*)(gp), \
    (__attribute__((address_space(3))) void*)(lp), 16, 0, 0)

// ---- prep: elementwise split fp32 -> (hi, lo) bf16, same layout -----------
__global__ __launch_bounds__(256) void split_hl(
    const float* __restrict__ in, unsigned short* __restrict__ hi,
    unsigned short* __restrict__ lo, int n4)
{
    int i = blockIdx.x * 256 + threadIdx.x;
    if (i >= n4) return;
    float4 v = reinterpret_cast<const float4*>(in)[i];
    ushort4 h, L;
    h.x = f2bf(v.x); L.x = f2bf(v.x - bf2f(h.x));
    h.y = f2bf(v.y); L.y = f2bf(v.y - bf2f(h.y));
    h.z = f2bf(v.z); L.z = f2bf(v.z - bf2f(h.z));
    h.w = f2bf(v.w); L.w = f2bf(v.w - bf2f(h.w));
    reinterpret_cast<ushort4*>(hi)[i] = h;
    reinterpret_cast<ushort4*>(lo)[i] = L;
}

// ---- prep: split + transpose: in[K][N] fp32 -> hiT/loT[N][K] bf16 ---------
__global__ __launch_bounds__(256) void splitT_hl(
    const float* __restrict__ in, unsigned short* __restrict__ hiT,
    unsigned short* __restrict__ loT, int K, int N)
{
    __shared__ float t[32][33];
    const int n0 = blockIdx.x * 32, k0 = blockIdx.y * 32;
    const int tx = threadIdx.x & 31, ty = threadIdx.x >> 5;   // 32 x 8
    #pragma unroll
    for (int r = 0; r < 32; r += 8)
        t[ty + r][tx] = in[(size_t)(k0 + ty + r) * N + n0 + tx];
    __syncthreads();
    #pragma unroll
    for (int r = 0; r < 32; r += 8) {
        float v = t[tx][ty + r];
        unsigned short h = f2bf(v);
        size_t o = (size_t)(n0 + ty + r) * K + k0 + tx;
        hiT[o] = h;
        loT[o] = f2bf(v - bf2f(h));
    }
}

// ---- prep: V transpose: qkv V-section -> Vt[bh][d][seq] bf16 hi/lo --------
__global__ __launch_bounds__(256) void vt_prep(
    const float* __restrict__ qkv,
    unsigned short* __restrict__ Vth, unsigned short* __restrict__ Vtl)
{
    __shared__ float t[32][33];
    const int s0 = blockIdx.x * 32, d0 = blockIdx.y * 32, bh = blockIdx.z;
    const int b = bh >> 4, h = bh & 15;
    const int tx = threadIdx.x & 31, ty = threadIdx.x >> 5;
    #pragma unroll
    for (int r = 0; r < 32; r += 8)
        t[ty + r][tx] = qkv[((size_t)b * SEQ + s0 + ty + r) * 3072 + 2048 + h * 64 + d0 + tx];
    __syncthreads();
    #pragma unroll
    for (int r = 0; r < 32; r += 8) {
        float v = t[tx][ty + r];                       // (s = s0+tx, d = d0+ty+r)
        unsigned short hh = f2bf(v);
        size_t o = ((size_t)bh * 64 + d0 + ty + r) * SEQ + s0 + tx;
        Vth[o] = hh;
        Vtl[o] = f2bf(v - bf2f(hh));
    }
}

// ---- split-bf16 3-pass MFMA GEMM: C[M,N] = A @ B^T (+bias) ----------------
__global__ __launch_bounds__(256) void gemm_bt_3p(
    const unsigned short* __restrict__ Ah, const unsigned short* __restrict__ Al,
    const unsigned short* __restrict__ Bh, const unsigned short* __restrict__ Bl,
    const float* __restrict__ bias, float* __restrict__ C,
    int M, int N, int K)
{
    __shared__ __align__(16) unsigned short sAh[128 * 32];
    __shared__ __align__(16) unsigned short sAl[128 * 32];
    __shared__ __align__(16) unsigned short sBh[128 * 32];
    __shared__ __align__(16) unsigned short sBl[128 * 32];

    const int tid = threadIdx.x;
    const int l = tid & 63, w = tid >> 6;
    const int wr = w >> 1, wc = w & 1;
    const int bm = blockIdx.x * 128, bn = blockIdx.y * 128;

    const int srow = w * 32 + (l >> 2);
    const int scol = (l & 3) * 8;
    const size_t a0 = (size_t)(bm + srow) * K + scol;
    const size_t a1 = (size_t)(bm + srow + 16) * K + scol;
    const size_t b0 = (size_t)(bn + srow) * K + scol;
    const size_t b1 = (size_t)(bn + srow + 16) * K + scol;

    const int fr = l & 15;
    const int fk = (l >> 4) * 8;

    f32x4 acc[4][4];
    #pragma unroll
    for (int i = 0; i < 4; ++i)
        #pragma unroll
        for (int j = 0; j < 4; ++j)
            acc[i][j] = (f32x4){0.f, 0.f, 0.f, 0.f};

    for (int k0 = 0; k0 < K; k0 += 32) {
        __syncthreads();
        GLD(Ah + a0 + k0, sAh + w * 1024);
        GLD(Ah + a1 + k0, sAh + w * 1024 + 512);
        GLD(Al + a0 + k0, sAl + w * 1024);
        GLD(Al + a1 + k0, sAl + w * 1024 + 512);
        GLD(Bh + b0 + k0, sBh + w * 1024);
        GLD(Bh + b1 + k0, sBh + w * 1024 + 512);
        GLD(Bl + b0 + k0, sBl + w * 1024);
        GLD(Bl + b1 + k0, sBl + w * 1024 + 512);
        __syncthreads();

        short8 vah[4], val[4], vbh[4], vbl[4];
        #pragma unroll
        for (int i = 0; i < 4; ++i) {
            int ar = (wr * 64 + i * 16 + fr) * 32 + fk;
            int br = (wc * 64 + i * 16 + fr) * 32 + fk;
            vah[i] = *reinterpret_cast<const short8*>(&sAh[ar]);
            val[i] = *reinterpret_cast<const short8*>(&sAl[ar]);
            vbh[i] = *reinterpret_cast<const short8*>(&sBh[br]);
            vbl[i] = *reinterpret_cast<const short8*>(&sBl[br]);
        }
        #pragma unroll
        for (int i = 0; i < 4; ++i)
            #pragma unroll
            for (int j = 0; j < 4; ++j) {
                acc[i][j] = __builtin_amdgcn_mfma_f32_16x16x32_bf16(vah[i], vbh[j], acc[i][j], 0, 0, 0);
                acc[i][j] = __builtin_amdgcn_mfma_f32_16x16x32_bf16(vah[i], vbl[j], acc[i][j], 0, 0, 0);
                acc[i][j] = __builtin_amdgcn_mfma_f32_16x16x32_bf16(val[i], vbh[j], acc[i][j], 0, 0, 0);
            }
    }

    #pragma unroll
    for (int i = 0; i < 4; ++i) {
        #pragma unroll
        for (int j = 0; j < 4; ++j) {
            int row = bm + wr * 64 + i * 16 + (l >> 4) * 4;
            int col = bn + wc * 64 + j * 16 + fr;
            float bb = bias ? bias[col] : 0.f;
            #pragma unroll
            for (int r = 0; r < 4; ++r)
                C[(size_t)(row + r) * N + col] = acc[i][j][r] + bb;
        }
    }
}

// ---- MFMA flash attention: 64 Q-rows/block, 4 waves x 16-row strips -------
__global__ __launch_bounds__(256) void flash_attn_mfma(
    const float* __restrict__ qkv,
    const unsigned short* __restrict__ Vth, const unsigned short* __restrict__ Vtl,
    unsigned short* __restrict__ out_hi, unsigned short* __restrict__ out_lo)
{
    __shared__ __align__(16) unsigned short sQh[64 * 64], sQl[64 * 64];
    __shared__ __align__(16) unsigned short sKh[64 * 64], sKl[64 * 64];
    __shared__ __align__(16) unsigned short sVh[64 * 64], sVl[64 * 64];
    __shared__ __align__(16) unsigned short sPh[64 * 64], sPl[64 * 64];

    const int qt = blockIdx.x, h = blockIdx.y, b = blockIdx.z;
    const int tid = threadIdx.x;
    const int l = tid & 63, w = tid >> 6;
    const int fr = l & 15, g = l >> 4;

    // ---- stage Q (scaled, split, swizzled) ----
    const size_t qbase = ((size_t)b * SEQ + (size_t)qt * 64) * 3072 + h * 64;
    for (int idx = tid; idx < 64 * 16; idx += 256) {
        int r = idx >> 4, c4 = (idx & 15) * 4;
        float4 v = *reinterpret_cast<const float4*>(qkv + qbase + (size_t)r * 3072 + c4);
        v.x *= 0.125f; v.y *= 0.125f; v.z *= 0.125f; v.w *= 0.125f;
        ushort4 hi, lo;
        hi.x = f2bf(v.x); lo.x = f2bf(v.x - bf2f(hi.x));
        hi.y = f2bf(v.y); lo.y = f2bf(v.y - bf2f(hi.y));
        hi.z = f2bf(v.z); lo.z = f2bf(v.z - bf2f(hi.z));
        hi.w = f2bf(v.w); lo.w = f2bf(v.w - bf2f(hi.w));
        int off = swz(r, c4 * 2);
        *reinterpret_cast<ushort4*>((char*)sQh + off) = hi;
        *reinterpret_cast<ushort4*>((char*)sQl + off) = lo;
    }

    float m_[4], l_[4];
    f32x4 oacc[4];
    #pragma unroll
    for (int r = 0; r < 4; ++r) { m_[r] = -1e30f; l_[r] = 0.f; }
    #pragma unroll
    for (int d = 0; d < 4; ++d) oacc[d] = (f32x4){0.f, 0.f, 0.f, 0.f};

    const size_t kbase = (size_t)b * SEQ * 3072 + 1024 + h * 64;
    const size_t vtb = ((size_t)(b * NH + h)) * 64 * SEQ;    // element offset

    for (int kt = 0; kt < SEQ / 64; ++kt) {
        __syncthreads();
        // ---- stage K (split, swizzled) ----
        for (int idx = tid; idx < 64 * 16; idx += 256) {
            int r = idx >> 4, c4 = (idx & 15) * 4;
            float4 v = *reinterpret_cast<const float4*>(
                qkv + kbase + ((size_t)kt * 64 + r) * 3072 + c4);
            ushort4 hi, lo;
            hi.x = f2bf(v.x); lo.x = f2bf(v.x - bf2f(hi.x));
            hi.y = f2bf(v.y); lo.y = f2bf(v.y - bf2f(hi.y));
            hi.z = f2bf(v.z); lo.z = f2bf(v.z - bf2f(hi.z));
            hi.w = f2bf(v.w); lo.w = f2bf(v.w - bf2f(hi.w));
            int off = swz(r, c4 * 2);
            *reinterpret_cast<ushort4*>((char*)sKh + off) = hi;
            *reinterpret_cast<ushort4*>((char*)sKl + off) = lo;
        }
        // ---- stage V via global_load_lds, pre-swizzled source (m173) ----
        #pragma unroll
        for (int i2 = 0; i2 < 2; ++i2) {
            int i = w * 2 + i2;
            int gi = i * 64 + l;               // 16B chunk index in tile
            int r = gi >> 3, c = gi & 7;
            int cs = c ^ (r & 7);              // inverse-swizzled source chunk
            size_t go = vtb + (size_t)r * SEQ + (size_t)kt * 64 + cs * 8;
            GLD(Vth + go, (unsigned short*)((char*)sVh + i * 1024));
            GLD(Vtl + go, (unsigned short*)((char*)sVl + i * 1024));
        }
        __syncthreads();

        // ---- S = Q K^T (3-pass split) ----
        f32x4 sacc[4];
        #pragma unroll
        for (int jf = 0; jf < 4; ++jf) sacc[jf] = (f32x4){0.f, 0.f, 0.f, 0.f};
        #pragma unroll
        for (int ks = 0; ks < 2; ++ks) {
            int ccol = (ks * 32 + g * 8) * 2;   // byte col
            int arow = w * 16 + fr;
            short8 ah = *reinterpret_cast<const short8*>((char*)sQh + swz(arow, ccol));
            short8 al = *reinterpret_cast<const short8*>((char*)sQl + swz(arow, ccol));
            #pragma unroll
            for (int jf = 0; jf < 4; ++jf) {
                int brow = jf * 16 + fr;
                short8 bh = *reinterpret_cast<const short8*>((char*)sKh + swz(brow, ccol));
                short8 bl = *reinterpret_cast<const short8*>((char*)sKl + swz(brow, ccol));
                sacc[jf] = __builtin_amdgcn_mfma_f32_16x16x32_bf16(ah, bh, sacc[jf], 0, 0, 0);
                sacc[jf] = __builtin_amdgcn_mfma_f32_16x16x32_bf16(ah, bl, sacc[jf], 0, 0, 0);
                sacc[jf] = __builtin_amdgcn_mfma_f32_16x16x32_bf16(al, bh, sacc[jf], 0, 0, 0);
            }
        }

        // ---- online softmax; P -> LDS (hi/lo, swizzled) ----
        #pragma unroll
        for (int r = 0; r < 4; ++r) {
            float mx = fmaxf(fmaxf(sacc[0][r], sacc[1][r]), fmaxf(sacc[2][r], sacc[3][r]));
            #pragma unroll
            for (int off = 1; off < 16; off <<= 1)
                mx = fmaxf(mx, __shfl_xor(mx, off));
            float mnew  = fmaxf(m_[r], mx);
            float alpha = __expf(m_[r] - mnew);
            m_[r] = mnew;
            float rs = 0.f;
            int rowg = w * 16 + g * 4 + r;
            #pragma unroll
            for (int jf = 0; jf < 4; ++jf) {
                float p = __expf(sacc[jf][r] - mnew);
                rs += p;
                unsigned short ph = f2bf(p);
                unsigned short pl = f2bf(p - bf2f(ph));
                int off2 = rowg * 128 + (((jf * 16 + fr) * 2) ^ ((rowg & 7) << 4));
                *reinterpret_cast<unsigned short*>((char*)sPh + off2) = ph;
                *reinterpret_cast<unsigned short*>((char*)sPl + off2) = pl;
            }
            #pragma unroll
            for (int off = 1; off < 16; off <<= 1)
                rs += __shfl_xor(rs, off);
            l_[r] = l_[r] * alpha + rs;
            #pragma unroll
            for (int df = 0; df < 4; ++df) oacc[df][r] *= alpha;
        }
        asm volatile("s_waitcnt lgkmcnt(0)" ::: "memory");
        __builtin_amdgcn_sched_barrier(0);

        // ---- O += P V (3-pass split) ----
        #pragma unroll
        for (int ks = 0; ks < 2; ++ks) {
            int kcol = (ks * 32 + g * 8) * 2;
            int prow = w * 16 + fr;
            short8 pah = *reinterpret_cast<const short8*>((char*)sPh + swz(prow, kcol));
            short8 pal = *reinterpret_cast<const short8*>((char*)sPl + swz(prow, kcol));
            #pragma unroll
            for (int df = 0; df < 4; ++df) {
                int vrow = df * 16 + fr;
                short8 vbh = *reinterpret_cast<const short8*>((char*)sVh + swz(vrow, kcol));
                short8 vbl = *reinterpret_cast<const short8*>((char*)sVl + swz(vrow, kcol));
                oacc[df] = __builtin_amdgcn_mfma_f32_16x16x32_bf16(pah, vbh, oacc[df], 0, 0, 0);
                oacc[df] = __builtin_amdgcn_mfma_f32_16x16x32_bf16(pah, vbl, oacc[df], 0, 0, 0);
                oacc[df] = __builtin_amdgcn_mfma_f32_16x16x32_bf16(pal, vbh, oacc[df], 0, 0, 0);
            }
        }
    }

    // ---- epilogue: O/l -> hi/lo bf16 ----
    #pragma unroll
    for (int r = 0; r < 4; ++r) {
        float inv = 1.f / l_[r];
        int row = qt * 64 + w * 16 + g * 4 + r;
        #pragma unroll
        for (int df = 0; df < 4; ++df) {
            float v = oacc[df][r] * inv;
            unsigned short hh = f2bf(v);
            size_t o = ((size_t)b * SEQ + row) * DM + h * 64 + df * 16 + fr;
            out_hi[o] = hh;
            out_lo[o] = f2bf(v - bf2f(hh));
        }
    }
}

extern "C" void kernel_launch(void* const* d_in, const int* in_sizes, int n_in,
                              void* d_out, int out_size, void* d_ws, size_t ws_size,
                              hipStream_t stream) {
    const float* x     = (const float*)d_in[0];
    const float* w_qkv = (const float*)d_in[1];
    const float* w_out = (const float*)d_in[2];
    const float* b_out = (const float*)d_in[3];
    float* out = (float*)d_out;

    const int M = BATCH * SEQ;                    // 8192

    char* ws = (char*)d_ws;
    float*          qkv   = (float*)ws;                                  ws += (size_t)M * 3072 * 4;
    unsigned short* x_hi  = (unsigned short*)ws;                         ws += (size_t)M * DM * 2;
    unsigned short* x_lo  = (unsigned short*)ws;                         ws += (size_t)M * DM * 2;
    unsigned short* wqT_h = (unsigned short*)ws;                         ws += (size_t)3072 * DM * 2;
    unsigned short* wqT_l = (unsigned short*)ws;                         ws += (size_t)3072 * DM * 2;
    unsigned short* woT_h = (unsigned short*)ws;                         ws += (size_t)DM * DM * 2;
    unsigned short* woT_l = (unsigned short*)ws;                         ws += (size_t)DM * DM * 2;
    unsigned short* at_hi = (unsigned short*)ws;                         ws += (size_t)M * DM * 2;
    unsigned short* at_lo = (unsigned short*)ws;

    // V-transpose buffers alias x_hi/x_lo (dead after GEMM1; same size 16.8MB)
    unsigned short* Vth = x_hi;
    unsigned short* Vtl = x_lo;

    dim3 blk(256);

    split_hl<<<dim3((M * DM / 4 + 255) / 256), blk, 0, stream>>>(x, x_hi, x_lo, M * DM / 4);
    splitT_hl<<<dim3(3072 / 32, DM / 32), blk, 0, stream>>>(w_qkv, wqT_h, wqT_l, DM, 3 * DM);
    splitT_hl<<<dim3(DM / 32, DM / 32), blk, 0, stream>>>(w_out, woT_h, woT_l, DM, DM);

    // 1) qkv = x @ w_qkv
    gemm_bt_3p<<<dim3(M / 128, 3 * DM / 128), blk, 0, stream>>>(
        x_hi, x_lo, wqT_h, wqT_l, nullptr, qkv, M, 3 * DM, DM);

    // 2a) V transpose prep (overwrites x_hi/x_lo)
    vt_prep<<<dim3(SEQ / 32, DH / 32, BATCH * NH), blk, 0, stream>>>(qkv, Vth, Vtl);

    // 2b) MFMA flash attention
    flash_attn_mfma<<<dim3(SEQ / 64, NH, BATCH), blk, 0, stream>>>(
        qkv, Vth, Vtl, at_hi, at_lo);

    // 3) out = attn @ w_out + b_out
    gemm_bt_3p<<<dim3(M / 128, DM / 128), blk, 0, stream>>>(
        at_hi, at_lo, woT_h, woT_l, b_out, out, M, DM, DM);
}

// Round 4
// 626.286 us; speedup vs baseline: 3.5513x; 1.2135x over previous
//
#include <hip/hip_runtime.h>
#include <math.h>

#define DM   1024
#define NH   16
#define DH   64
#define SEQ  2048
#define BATCH 4

typedef __attribute__((ext_vector_type(8))) short  short8;
typedef __attribute__((ext_vector_type(4))) float  f32x4;

// ---- fp32 -> bf16 hi/lo split helpers (RNE) -------------------------------
static __device__ __forceinline__ unsigned short f2bf(float f) {
    unsigned u = __float_as_uint(f);
    unsigned r = (u + 0x7fffu + ((u >> 16) & 1u)) >> 16;
    return (unsigned short)r;
}
static __device__ __forceinline__ float bf2f(unsigned short h) {
    return __uint_as_float(((unsigned)h) << 16);
}

// swizzled byte offset inside a [64 rows][128B] LDS tile (T2-style, G4 rule)
static __device__ __forceinline__ int swz(int row, int cbyte) {
    return row * 128 + (cbyte ^ ((row & 7) << 4));
}

#define GLD(gp, lp) __builtin_amdgcn_global_load_lds( \
    (const __attribute__((address_space(1))) void*)(gp), \
    (__attribute__((address_space(3))) void*)(lp), 16, 0, 0)

// ---- prep: elementwise split fp32 -> (hi, lo) bf16, same layout -----------
__global__ __launch_bounds__(256) void split_hl(
    const float* __restrict__ in, unsigned short* __restrict__ hi,
    unsigned short* __restrict__ lo, int n4)
{
    int i = blockIdx.x * 256 + threadIdx.x;
    if (i >= n4) return;
    float4 v = reinterpret_cast<const float4*>(in)[i];
    ushort4 h, L;
    h.x = f2bf(v.x); L.x = f2bf(v.x - bf2f(h.x));
    h.y = f2bf(v.y); L.y = f2bf(v.y - bf2f(h.y));
    h.z = f2bf(v.z); L.z = f2bf(v.z - bf2f(h.z));
    h.w = f2bf(v.w); L.w = f2bf(v.w - bf2f(h.w));
    reinterpret_cast<ushort4*>(hi)[i] = h;
    reinterpret_cast<ushort4*>(lo)[i] = L;
}

// ---- prep: split + transpose: in[K][N] fp32 -> hiT/loT[N][K] bf16 ---------
__global__ __launch_bounds__(256) void splitT_hl(
    const float* __restrict__ in, unsigned short* __restrict__ hiT,
    unsigned short* __restrict__ loT, int K, int N)
{
    __shared__ float t[32][33];
    const int n0 = blockIdx.x * 32, k0 = blockIdx.y * 32;
    const int tx = threadIdx.x & 31, ty = threadIdx.x >> 5;
    #pragma unroll
    for (int r = 0; r < 32; r += 8)
        t[ty + r][tx] = in[(size_t)(k0 + ty + r) * N + n0 + tx];
    __syncthreads();
    #pragma unroll
    for (int r = 0; r < 32; r += 8) {
        float v = t[tx][ty + r];
        unsigned short h = f2bf(v);
        size_t o = (size_t)(n0 + ty + r) * K + k0 + tx;
        hiT[o] = h;
        loT[o] = f2bf(v - bf2f(h));
    }
}

// ---- prep: V transpose (bf16 hi/lo): qkv V-section -> Vt[bh][d][seq] ------
__global__ __launch_bounds__(256) void vt_prep_bf(
    const unsigned short* __restrict__ qh, const unsigned short* __restrict__ ql,
    unsigned short* __restrict__ Vth, unsigned short* __restrict__ Vtl)
{
    __shared__ unsigned short th[32][34], tl[32][34];
    const int s0 = blockIdx.x * 32, d0 = blockIdx.y * 32, bh = blockIdx.z;
    const int b = bh >> 4, h = bh & 15;
    const int tx = threadIdx.x & 31, ty = threadIdx.x >> 5;
    #pragma unroll
    for (int r = 0; r < 32; r += 8) {
        size_t src = ((size_t)b * SEQ + s0 + ty + r) * 3072 + 2048 + h * 64 + d0 + tx;
        th[ty + r][tx] = qh[src];
        tl[ty + r][tx] = ql[src];
    }
    __syncthreads();
    #pragma unroll
    for (int r = 0; r < 32; r += 8) {
        size_t o = ((size_t)bh * 64 + d0 + ty + r) * SEQ + s0 + tx;
        Vth[o] = th[tx][ty + r];
        Vtl[o] = tl[tx][ty + r];
    }
}

// ---- split-bf16 3-pass MFMA GEMM core (shared macro-ish via template) -----
// MODE 0: C fp32 + bias.  MODE 1: C -> hi/lo bf16, cols<1024 scaled by 0.125.
template <int MODE>
__global__ __launch_bounds__(256) void gemm_bt_3p_t(
    const unsigned short* __restrict__ Ah, const unsigned short* __restrict__ Al,
    const unsigned short* __restrict__ Bh, const unsigned short* __restrict__ Bl,
    const float* __restrict__ bias, float* __restrict__ C,
    unsigned short* __restrict__ Ch, unsigned short* __restrict__ Cl,
    int M, int N, int K)
{
    __shared__ __align__(16) unsigned short sAh[128 * 32];
    __shared__ __align__(16) unsigned short sAl[128 * 32];
    __shared__ __align__(16) unsigned short sBh[128 * 32];
    __shared__ __align__(16) unsigned short sBl[128 * 32];

    const int tid = threadIdx.x;
    const int l = tid & 63, w = tid >> 6;
    const int wr = w >> 1, wc = w & 1;
    const int bm = blockIdx.x * 128, bn = blockIdx.y * 128;

    const int srow = w * 32 + (l >> 2);
    const int scol = (l & 3) * 8;
    const size_t a0 = (size_t)(bm + srow) * K + scol;
    const size_t a1 = (size_t)(bm + srow + 16) * K + scol;
    const size_t b0 = (size_t)(bn + srow) * K + scol;
    const size_t b1 = (size_t)(bn + srow + 16) * K + scol;

    const int fr = l & 15;
    const int fk = (l >> 4) * 8;

    f32x4 acc[4][4];
    #pragma unroll
    for (int i = 0; i < 4; ++i)
        #pragma unroll
        for (int j = 0; j < 4; ++j)
            acc[i][j] = (f32x4){0.f, 0.f, 0.f, 0.f};

    for (int k0 = 0; k0 < K; k0 += 32) {
        __syncthreads();
        GLD(Ah + a0 + k0, sAh + w * 1024);
        GLD(Ah + a1 + k0, sAh + w * 1024 + 512);
        GLD(Al + a0 + k0, sAl + w * 1024);
        GLD(Al + a1 + k0, sAl + w * 1024 + 512);
        GLD(Bh + b0 + k0, sBh + w * 1024);
        GLD(Bh + b1 + k0, sBh + w * 1024 + 512);
        GLD(Bl + b0 + k0, sBl + w * 1024);
        GLD(Bl + b1 + k0, sBl + w * 1024 + 512);
        __syncthreads();

        short8 vah[4], val[4], vbh[4], vbl[4];
        #pragma unroll
        for (int i = 0; i < 4; ++i) {
            int ar = (wr * 64 + i * 16 + fr) * 32 + fk;
            int br = (wc * 64 + i * 16 + fr) * 32 + fk;
            vah[i] = *reinterpret_cast<const short8*>(&sAh[ar]);
            val[i] = *reinterpret_cast<const short8*>(&sAl[ar]);
            vbh[i] = *reinterpret_cast<const short8*>(&sBh[br]);
            vbl[i] = *reinterpret_cast<const short8*>(&sBl[br]);
        }
        __builtin_amdgcn_s_setprio(1);
        #pragma unroll
        for (int i = 0; i < 4; ++i)
            #pragma unroll
            for (int j = 0; j < 4; ++j) {
                acc[i][j] = __builtin_amdgcn_mfma_f32_16x16x32_bf16(vah[i], vbh[j], acc[i][j], 0, 0, 0);
                acc[i][j] = __builtin_amdgcn_mfma_f32_16x16x32_bf16(vah[i], vbl[j], acc[i][j], 0, 0, 0);
                acc[i][j] = __builtin_amdgcn_mfma_f32_16x16x32_bf16(val[i], vbh[j], acc[i][j], 0, 0, 0);
            }
        __builtin_amdgcn_s_setprio(0);
    }

    #pragma unroll
    for (int i = 0; i < 4; ++i) {
        #pragma unroll
        for (int j = 0; j < 4; ++j) {
            int row = bm + wr * 64 + i * 16 + (l >> 4) * 4;
            int col = bn + wc * 64 + j * 16 + fr;
            if (MODE == 0) {
                float bb = bias ? bias[col] : 0.f;
                #pragma unroll
                for (int r = 0; r < 4; ++r)
                    C[(size_t)(row + r) * N + col] = acc[i][j][r] + bb;
            } else {
                float sc = (col < 1024) ? 0.125f : 1.0f;
                #pragma unroll
                for (int r = 0; r < 4; ++r) {
                    float v = acc[i][j][r] * sc;
                    unsigned short hh = f2bf(v);
                    size_t o = (size_t)(row + r) * N + col;
                    Ch[o] = hh;
                    Cl[o] = f2bf(v - bf2f(hh));
                }
            }
        }
    }
}

// ---- MFMA flash attention: reg-Q, GLD-staged K/V dbuf, 1 barrier/tile -----
__global__ __launch_bounds__(256) void flash_attn_mfma(
    const unsigned short* __restrict__ QKh, const unsigned short* __restrict__ QKl,
    const unsigned short* __restrict__ Vth, const unsigned short* __restrict__ Vtl,
    unsigned short* __restrict__ out_hi, unsigned short* __restrict__ out_lo)
{
    __shared__ __align__(16) unsigned short sK[2][2][64 * 64];  // [buf][hi/lo]
    __shared__ __align__(16) unsigned short sV[2][2][64 * 64];
    __shared__ __align__(16) unsigned short sP[2][64 * 64];     // [hi/lo]

    const int qt = blockIdx.x, h = blockIdx.y, b = blockIdx.z;
    const int tid = threadIdx.x;
    const int l = tid & 63, w = tid >> 6;
    const int fr = l & 15, g = l >> 4;

    const size_t kgbase = (size_t)b * SEQ * 3072 + 1024 + h * 64;
    const size_t vtb    = ((size_t)(b * NH + h)) * 64 * SEQ;

    // per-lane stage addressing: wave w covers chunk-issues i = 2w, 2w+1
    int sg_r[2], sg_c[2];
    #pragma unroll
    for (int i2 = 0; i2 < 2; ++i2) {
        int gi = (w * 2 + i2) * 64 + l;
        sg_r[i2] = gi >> 3;
        sg_c[i2] = (gi & 7) ^ (sg_r[i2] & 7);    // inverse-swizzled source chunk
    }

    #define STAGE_TILE(cbuf, kt_) do {                                         \
        _Pragma("unroll")                                                      \
        for (int i2 = 0; i2 < 2; ++i2) {                                       \
            int i = w * 2 + i2;                                                \
            size_t gk = kgbase + (size_t)((kt_) * 64 + sg_r[i2]) * 3072 + sg_c[i2] * 8; \
            size_t gv = vtb + (size_t)sg_r[i2] * SEQ + (size_t)(kt_) * 64 + sg_c[i2] * 8; \
            GLD(QKh + gk, (char*)&sK[cbuf][0][0] + i * 1024);                  \
            GLD(QKl + gk, (char*)&sK[cbuf][1][0] + i * 1024);                  \
            GLD(Vth + gv, (char*)&sV[cbuf][0][0] + i * 1024);                  \
            GLD(Vtl + gv, (char*)&sV[cbuf][1][0] + i * 1024);                  \
        }                                                                      \
    } while (0)

    // ---- Q fragments direct to registers (pre-scaled in GEMM1 epilogue) ----
    short8 qh[2], ql[2];
    {
        const int qrow = qt * 64 + w * 16 + fr;
        const size_t qb = ((size_t)b * SEQ + qrow) * 3072 + h * 64;
        #pragma unroll
        for (int ks = 0; ks < 2; ++ks) {
            qh[ks] = *reinterpret_cast<const short8*>(QKh + qb + ks * 32 + g * 8);
            ql[ks] = *reinterpret_cast<const short8*>(QKl + qb + ks * 32 + g * 8);
        }
    }

    float m_[4], l_[4];
    f32x4 oacc[4];
    #pragma unroll
    for (int r = 0; r < 4; ++r) { m_[r] = -1e30f; l_[r] = 0.f; }
    #pragma unroll
    for (int d = 0; d < 4; ++d) oacc[d] = (f32x4){0.f, 0.f, 0.f, 0.f};

    STAGE_TILE(0, 0);
    int cur = 0;

    for (int kt = 0; kt < SEQ / 64; ++kt) {
        __syncthreads();                      // buf[cur] ready; prev reads done
        if (kt + 1 < SEQ / 64) STAGE_TILE(cur ^ 1, kt + 1);

        const unsigned short* kh = &sK[cur][0][0];
        const unsigned short* kl = &sK[cur][1][0];
        const unsigned short* vh = &sV[cur][0][0];
        const unsigned short* vl = &sV[cur][1][0];

        // ---- S = Q K^T (3-pass split) ----
        f32x4 sacc[4];
        #pragma unroll
        for (int jf = 0; jf < 4; ++jf) sacc[jf] = (f32x4){0.f, 0.f, 0.f, 0.f};
        #pragma unroll
        for (int ks = 0; ks < 2; ++ks) {
            int ccol = (ks * 32 + g * 8) * 2;
            #pragma unroll
            for (int jf = 0; jf < 4; ++jf) {
                int brow = jf * 16 + fr;
                short8 bh = *reinterpret_cast<const short8*>((const char*)kh + swz(brow, ccol));
                short8 bl = *reinterpret_cast<const short8*>((const char*)kl + swz(brow, ccol));
                __builtin_amdgcn_s_setprio(1);
                sacc[jf] = __builtin_amdgcn_mfma_f32_16x16x32_bf16(qh[ks], bh, sacc[jf], 0, 0, 0);
                sacc[jf] = __builtin_amdgcn_mfma_f32_16x16x32_bf16(qh[ks], bl, sacc[jf], 0, 0, 0);
                sacc[jf] = __builtin_amdgcn_mfma_f32_16x16x32_bf16(ql[ks], bh, sacc[jf], 0, 0, 0);
                __builtin_amdgcn_s_setprio(0);
            }
        }

        // ---- online softmax; P -> LDS (hi/lo, swizzled) ----
        #pragma unroll
        for (int r = 0; r < 4; ++r) {
            float mx = fmaxf(fmaxf(sacc[0][r], sacc[1][r]), fmaxf(sacc[2][r], sacc[3][r]));
            #pragma unroll
            for (int off = 1; off < 16; off <<= 1)
                mx = fmaxf(mx, __shfl_xor(mx, off));
            float mnew  = fmaxf(m_[r], mx);
            float alpha = __expf(m_[r] - mnew);
            m_[r] = mnew;
            float rs = 0.f;
            int rowg = w * 16 + g * 4 + r;
            #pragma unroll
            for (int jf = 0; jf < 4; ++jf) {
                float p = __expf(sacc[jf][r] - mnew);
                rs += p;
                unsigned short ph = f2bf(p);
                unsigned short pl = f2bf(p - bf2f(ph));
                int off2 = rowg * 128 + (((jf * 16 + fr) * 2) ^ ((rowg & 7) << 4));
                *reinterpret_cast<unsigned short*>((char*)&sP[0][0] + off2) = ph;
                *reinterpret_cast<unsigned short*>((char*)&sP[1][0] + off2) = pl;
            }
            #pragma unroll
            for (int off = 1; off < 16; off <<= 1)
                rs += __shfl_xor(rs, off);
            l_[r] = l_[r] * alpha + rs;
            #pragma unroll
            for (int df = 0; df < 4; ++df) oacc[df][r] *= alpha;
        }
        asm volatile("s_waitcnt lgkmcnt(0)" ::: "memory");
        __builtin_amdgcn_sched_barrier(0);

        // ---- O += P V (3-pass split) ----
        #pragma unroll
        for (int ks = 0; ks < 2; ++ks) {
            int kcol = (ks * 32 + g * 8) * 2;
            int prow = w * 16 + fr;
            short8 pah = *reinterpret_cast<const short8*>((char*)&sP[0][0] + swz(prow, kcol));
            short8 pal = *reinterpret_cast<const short8*>((char*)&sP[1][0] + swz(prow, kcol));
            #pragma unroll
            for (int df = 0; df < 4; ++df) {
                int vrow = df * 16 + fr;
                short8 vbh = *reinterpret_cast<const short8*>((const char*)vh + swz(vrow, kcol));
                short8 vbl = *reinterpret_cast<const short8*>((const char*)vl + swz(vrow, kcol));
                __builtin_amdgcn_s_setprio(1);
                oacc[df] = __builtin_amdgcn_mfma_f32_16x16x32_bf16(pah, vbh, oacc[df], 0, 0, 0);
                oacc[df] = __builtin_amdgcn_mfma_f32_16x16x32_bf16(pah, vbl, oacc[df], 0, 0, 0);
                oacc[df] = __builtin_amdgcn_mfma_f32_16x16x32_bf16(pal, vbh, oacc[df], 0, 0, 0);
                __builtin_amdgcn_s_setprio(0);
            }
        }
        cur ^= 1;
    }

    // ---- epilogue: O/l -> hi/lo bf16 ----
    #pragma unroll
    for (int r = 0; r < 4; ++r) {
        float inv = 1.f / l_[r];
        int row = qt * 64 + w * 16 + g * 4 + r;
        #pragma unroll
        for (int df = 0; df < 4; ++df) {
            float v = oacc[df][r] * inv;
            unsigned short hh = f2bf(v);
            size_t o = ((size_t)b * SEQ + row) * DM + h * 64 + df * 16 + fr;
            out_hi[o] = hh;
            out_lo[o] = f2bf(v - bf2f(hh));
        }
    }
    #undef STAGE_TILE
}

extern "C" void kernel_launch(void* const* d_in, const int* in_sizes, int n_in,
                              void* d_out, int out_size, void* d_ws, size_t ws_size,
                              hipStream_t stream) {
    const float* x     = (const float*)d_in[0];
    const float* w_qkv = (const float*)d_in[1];
    const float* w_out = (const float*)d_in[2];
    const float* b_out = (const float*)d_in[3];
    float* out = (float*)d_out;

    const int M = BATCH * SEQ;                    // 8192

    char* ws = (char*)d_ws;
    unsigned short* qkv_h = (unsigned short*)ws;                         ws += (size_t)M * 3072 * 2;
    unsigned short* qkv_l = (unsigned short*)ws;                         ws += (size_t)M * 3072 * 2;
    unsigned short* x_hi  = (unsigned short*)ws;                         ws += (size_t)M * DM * 2;
    unsigned short* x_lo  = (unsigned short*)ws;                         ws += (size_t)M * DM * 2;
    unsigned short* wqT_h = (unsigned short*)ws;                         ws += (size_t)3072 * DM * 2;
    unsigned short* wqT_l = (unsigned short*)ws;                         ws += (size_t)3072 * DM * 2;
    unsigned short* woT_h = (unsigned short*)ws;                         ws += (size_t)DM * DM * 2;
    unsigned short* woT_l = (unsigned short*)ws;                         ws += (size_t)DM * DM * 2;
    unsigned short* at_hi = (unsigned short*)ws;                         ws += (size_t)M * DM * 2;
    unsigned short* at_lo = (unsigned short*)ws;

    // V-transpose buffers alias x_hi/x_lo (dead after GEMM1; same size)
    unsigned short* Vth = x_hi;
    unsigned short* Vtl = x_lo;

    dim3 blk(256);

    split_hl<<<dim3((M * DM / 4 + 255) / 256), blk, 0, stream>>>(x, x_hi, x_lo, M * DM / 4);
    splitT_hl<<<dim3(3072 / 32, DM / 32), blk, 0, stream>>>(w_qkv, wqT_h, wqT_l, DM, 3 * DM);
    splitT_hl<<<dim3(DM / 32, DM / 32), blk, 0, stream>>>(w_out, woT_h, woT_l, DM, DM);

    // 1) qkv = x @ w_qkv -> hi/lo bf16, Q section pre-scaled by 0.125
    gemm_bt_3p_t<1><<<dim3(M / 128, 3 * DM / 128), blk, 0, stream>>>(
        x_hi, x_lo, wqT_h, wqT_l, nullptr, nullptr, qkv_h, qkv_l, M, 3 * DM, DM);

    // 2a) V transpose prep (overwrites x_hi/x_lo)
    vt_prep_bf<<<dim3(SEQ / 32, DH / 32, BATCH * NH), blk, 0, stream>>>(
        qkv_h, qkv_l, Vth, Vtl);

    // 2b) MFMA flash attention
    flash_attn_mfma<<<dim3(SEQ / 64, NH, BATCH), blk, 0, stream>>>(
        qkv_h, qkv_l, Vth, Vtl, at_hi, at_lo);

    // 3) out = attn @ w_out + b_out
    gemm_bt_3p_t<0><<<dim3(M / 128, DM / 128), blk, 0, stream>>>(
        at_hi, at_lo, woT_h, woT_l, b_out, out, nullptr, nullptr, M, DM, DM);
}

// Round 5
// 540.463 us; speedup vs baseline: 4.1152x; 1.1588x over previous
//
#include <hip/hip_runtime.h>
#include <math.h>

#define DM   1024
#define NH   16
#define DH   64
#define SEQ  2048
#define BATCH 4

typedef __attribute__((ext_vector_type(8))) short  short8;
typedef __attribute__((ext_vector_type(4))) float  f32x4;

// ---- fp32 -> bf16 hi/lo split helpers (RNE) -------------------------------
static __device__ __forceinline__ unsigned short f2bf(float f) {
    unsigned u = __float_as_uint(f);
    unsigned r = (u + 0x7fffu + ((u >> 16) & 1u)) >> 16;
    return (unsigned short)r;
}
static __device__ __forceinline__ float bf2f(unsigned short h) {
    return __uint_as_float(((unsigned)h) << 16);
}

// swizzled byte offset inside a [64 rows][128B] LDS tile (T2-style, G4 rule)
static __device__ __forceinline__ int swz(int row, int cbyte) {
    return row * 128 + (cbyte ^ ((row & 7) << 4));
}

#define GLD(gp, lp) __builtin_amdgcn_global_load_lds( \
    (const __attribute__((address_space(1))) void*)(gp), \
    (__attribute__((address_space(3))) void*)(lp), 16, 0, 0)

// ---- prep: elementwise split fp32 -> (hi, lo) bf16, same layout -----------
__global__ __launch_bounds__(256) void split_hl(
    const float* __restrict__ in, unsigned short* __restrict__ hi,
    unsigned short* __restrict__ lo, int n4)
{
    int i = blockIdx.x * 256 + threadIdx.x;
    if (i >= n4) return;
    float4 v = reinterpret_cast<const float4*>(in)[i];
    ushort4 h, L;
    h.x = f2bf(v.x); L.x = f2bf(v.x - bf2f(h.x));
    h.y = f2bf(v.y); L.y = f2bf(v.y - bf2f(h.y));
    h.z = f2bf(v.z); L.z = f2bf(v.z - bf2f(h.z));
    h.w = f2bf(v.w); L.w = f2bf(v.w - bf2f(h.w));
    reinterpret_cast<ushort4*>(hi)[i] = h;
    reinterpret_cast<ushort4*>(lo)[i] = L;
}

// ---- prep: split + transpose: in[K][N] fp32 -> hiT/loT[N][K] bf16 ---------
__global__ __launch_bounds__(256) void splitT_hl(
    const float* __restrict__ in, unsigned short* __restrict__ hiT,
    unsigned short* __restrict__ loT, int K, int N)
{
    __shared__ float t[32][33];
    const int n0 = blockIdx.x * 32, k0 = blockIdx.y * 32;
    const int tx = threadIdx.x & 31, ty = threadIdx.x >> 5;
    #pragma unroll
    for (int r = 0; r < 32; r += 8)
        t[ty + r][tx] = in[(size_t)(k0 + ty + r) * N + n0 + tx];
    __syncthreads();
    #pragma unroll
    for (int r = 0; r < 32; r += 8) {
        float v = t[tx][ty + r];
        unsigned short h = f2bf(v);
        size_t o = (size_t)(n0 + ty + r) * K + k0 + tx;
        hiT[o] = h;
        loT[o] = f2bf(v - bf2f(h));
    }
}

// ---- prep: V transpose (bf16 hi/lo): qkv V-section -> Vt[bh][d][seq] ------
__global__ __launch_bounds__(256) void vt_prep_bf(
    const unsigned short* __restrict__ qh, const unsigned short* __restrict__ ql,
    unsigned short* __restrict__ Vth, unsigned short* __restrict__ Vtl)
{
    __shared__ unsigned short th[32][34], tl[32][34];
    const int s0 = blockIdx.x * 32, d0 = blockIdx.y * 32, bh = blockIdx.z;
    const int b = bh >> 4, h = bh & 15;
    const int tx = threadIdx.x & 31, ty = threadIdx.x >> 5;
    #pragma unroll
    for (int r = 0; r < 32; r += 8) {
        size_t src = ((size_t)b * SEQ + s0 + ty + r) * 3072 + 2048 + h * 64 + d0 + tx;
        th[ty + r][tx] = qh[src];
        tl[ty + r][tx] = ql[src];
    }
    __syncthreads();
    #pragma unroll
    for (int r = 0; r < 32; r += 8) {
        size_t o = ((size_t)bh * 64 + d0 + ty + r) * SEQ + s0 + tx;
        Vth[o] = th[tx][ty + r];
        Vtl[o] = tl[tx][ty + r];
    }
}

// ---- split-bf16 3-pass MFMA GEMM core -------------------------------------
// MODE 0: C fp32 + bias.  MODE 1: C -> hi/lo bf16, cols<1024 scaled by 0.125.
template <int MODE>
__global__ __launch_bounds__(256) void gemm_bt_3p_t(
    const unsigned short* __restrict__ Ah, const unsigned short* __restrict__ Al,
    const unsigned short* __restrict__ Bh, const unsigned short* __restrict__ Bl,
    const float* __restrict__ bias, float* __restrict__ C,
    unsigned short* __restrict__ Ch, unsigned short* __restrict__ Cl,
    int M, int N, int K)
{
    __shared__ __align__(16) unsigned short sAh[128 * 32];
    __shared__ __align__(16) unsigned short sAl[128 * 32];
    __shared__ __align__(16) unsigned short sBh[128 * 32];
    __shared__ __align__(16) unsigned short sBl[128 * 32];

    const int tid = threadIdx.x;
    const int l = tid & 63, w = tid >> 6;
    const int wr = w >> 1, wc = w & 1;
    const int bm = blockIdx.x * 128, bn = blockIdx.y * 128;

    const int srow = w * 32 + (l >> 2);
    const int scol = (l & 3) * 8;
    const size_t a0 = (size_t)(bm + srow) * K + scol;
    const size_t a1 = (size_t)(bm + srow + 16) * K + scol;
    const size_t b0 = (size_t)(bn + srow) * K + scol;
    const size_t b1 = (size_t)(bn + srow + 16) * K + scol;

    const int fr = l & 15;
    const int fk = (l >> 4) * 8;

    f32x4 acc[4][4];
    #pragma unroll
    for (int i = 0; i < 4; ++i)
        #pragma unroll
        for (int j = 0; j < 4; ++j)
            acc[i][j] = (f32x4){0.f, 0.f, 0.f, 0.f};

    for (int k0 = 0; k0 < K; k0 += 32) {
        __syncthreads();
        GLD(Ah + a0 + k0, sAh + w * 1024);
        GLD(Ah + a1 + k0, sAh + w * 1024 + 512);
        GLD(Al + a0 + k0, sAl + w * 1024);
        GLD(Al + a1 + k0, sAl + w * 1024 + 512);
        GLD(Bh + b0 + k0, sBh + w * 1024);
        GLD(Bh + b1 + k0, sBh + w * 1024 + 512);
        GLD(Bl + b0 + k0, sBl + w * 1024);
        GLD(Bl + b1 + k0, sBl + w * 1024 + 512);
        __syncthreads();

        short8 vah[4], val[4], vbh[4], vbl[4];
        #pragma unroll
        for (int i = 0; i < 4; ++i) {
            int ar = (wr * 64 + i * 16 + fr) * 32 + fk;
            int br = (wc * 64 + i * 16 + fr) * 32 + fk;
            vah[i] = *reinterpret_cast<const short8*>(&sAh[ar]);
            val[i] = *reinterpret_cast<const short8*>(&sAl[ar]);
            vbh[i] = *reinterpret_cast<const short8*>(&sBh[br]);
            vbl[i] = *reinterpret_cast<const short8*>(&sBl[br]);
        }
        __builtin_amdgcn_s_setprio(1);
        #pragma unroll
        for (int i = 0; i < 4; ++i)
            #pragma unroll
            for (int j = 0; j < 4; ++j) {
                acc[i][j] = __builtin_amdgcn_mfma_f32_16x16x32_bf16(vah[i], vbh[j], acc[i][j], 0, 0, 0);
                acc[i][j] = __builtin_amdgcn_mfma_f32_16x16x32_bf16(vah[i], vbl[j], acc[i][j], 0, 0, 0);
                acc[i][j] = __builtin_amdgcn_mfma_f32_16x16x32_bf16(val[i], vbh[j], acc[i][j], 0, 0, 0);
            }
        __builtin_amdgcn_s_setprio(0);
    }

    #pragma unroll
    for (int i = 0; i < 4; ++i) {
        #pragma unroll
        for (int j = 0; j < 4; ++j) {
            int row = bm + wr * 64 + i * 16 + (l >> 4) * 4;
            int col = bn + wc * 64 + j * 16 + fr;
            if (MODE == 0) {
                float bb = bias ? bias[col] : 0.f;
                #pragma unroll
                for (int r = 0; r < 4; ++r)
                    C[(size_t)(row + r) * N + col] = acc[i][j][r] + bb;
            } else {
                float sc = (col < 1024) ? 0.125f : 1.0f;
                #pragma unroll
                for (int r = 0; r < 4; ++r) {
                    float v = acc[i][j][r] * sc;
                    unsigned short hh = f2bf(v);
                    size_t o = (size_t)(row + r) * N + col;
                    Ch[o] = hh;
                    Cl[o] = f2bf(v - bf2f(hh));
                }
            }
        }
    }
}

// ---- MFMA flash attention: swapped QK^T, in-register softmax --------------
__global__ __launch_bounds__(256) void flash_attn_mfma(
    const unsigned short* __restrict__ QKh, const unsigned short* __restrict__ QKl,
    const unsigned short* __restrict__ Vth, const unsigned short* __restrict__ Vtl,
    unsigned short* __restrict__ out_hi, unsigned short* __restrict__ out_lo)
{
    __shared__ __align__(16) unsigned short sK[2][2][64 * 64];  // [buf][hi/lo]
    __shared__ __align__(16) unsigned short sV[2][2][64 * 64];
    __shared__ __align__(16) unsigned short sPh[64 * 64];
    __shared__ __align__(16) unsigned short sPl[64 * 64];

    const int qt = blockIdx.x, h = blockIdx.y, b = blockIdx.z;
    const int tid = threadIdx.x;
    const int l = tid & 63, w = tid >> 6;
    const int fr = l & 15, g = l >> 4;

    const size_t kgbase = (size_t)b * SEQ * 3072 + 1024 + h * 64;
    const size_t vtb    = ((size_t)(b * NH + h)) * 64 * SEQ;

    int sg_r[2], sg_c[2];
    #pragma unroll
    for (int i2 = 0; i2 < 2; ++i2) {
        int gi = (w * 2 + i2) * 64 + l;
        sg_r[i2] = gi >> 3;
        sg_c[i2] = (gi & 7) ^ (sg_r[i2] & 7);
    }

    #define STAGE_TILE(cbuf, kt_) do {                                         \
        _Pragma("unroll")                                                      \
        for (int i2 = 0; i2 < 2; ++i2) {                                       \
            int i = w * 2 + i2;                                                \
            size_t gk = kgbase + (size_t)((kt_) * 64 + sg_r[i2]) * 3072 + sg_c[i2] * 8; \
            size_t gv = vtb + (size_t)sg_r[i2] * SEQ + (size_t)(kt_) * 64 + sg_c[i2] * 8; \
            GLD(QKh + gk, (char*)&sK[cbuf][0][0] + i * 1024);                  \
            GLD(QKl + gk, (char*)&sK[cbuf][1][0] + i * 1024);                  \
            GLD(Vth + gv, (char*)&sV[cbuf][0][0] + i * 1024);                  \
            GLD(Vtl + gv, (char*)&sV[cbuf][1][0] + i * 1024);                  \
        }                                                                      \
    } while (0)

    // ---- Q fragments direct to registers (pre-scaled in GEMM1 epilogue) ----
    short8 qh[2], ql[2];
    {
        const int qrow = qt * 64 + w * 16 + fr;
        const size_t qb = ((size_t)b * SEQ + qrow) * 3072 + h * 64;
        #pragma unroll
        for (int ks = 0; ks < 2; ++ks) {
            qh[ks] = *reinterpret_cast<const short8*>(QKh + qb + ks * 32 + g * 8);
            ql[ks] = *reinterpret_cast<const short8*>(QKl + qb + ks * 32 + g * 8);
        }
    }

    float m_ = -1e30f, l_ = 0.f;       // softmax state for q-row w*16+fr
    f32x4 oacc[4];
    #pragma unroll
    for (int d = 0; d < 4; ++d) oacc[d] = (f32x4){0.f, 0.f, 0.f, 0.f};

    const int qrow_l = w * 16 + fr;    // P LDS row

    STAGE_TILE(0, 0);
    int cur = 0;

    for (int kt = 0; kt < SEQ / 64; ++kt) {
        __syncthreads();
        if (kt + 1 < SEQ / 64) STAGE_TILE(cur ^ 1, kt + 1);

        const unsigned short* kh = &sK[cur][0][0];
        const unsigned short* kl = &sK[cur][1][0];
        const unsigned short* vh = &sV[cur][0][0];
        const unsigned short* vl = &sV[cur][1][0];

        // ---- S^T = K Q^T (swapped operands; 3-pass split) ----
        // sacc[jf][r] = S[q = w*16+fr][key = jf*16 + g*4 + r]
        f32x4 sacc[4];
        #pragma unroll
        for (int jf = 0; jf < 4; ++jf) sacc[jf] = (f32x4){0.f, 0.f, 0.f, 0.f};
        #pragma unroll
        for (int ks = 0; ks < 2; ++ks) {
            int ccol = (ks * 32 + g * 8) * 2;
            #pragma unroll
            for (int jf = 0; jf < 4; ++jf) {
                int brow = jf * 16 + fr;
                short8 bh = *reinterpret_cast<const short8*>((const char*)kh + swz(brow, ccol));
                short8 bl = *reinterpret_cast<const short8*>((const char*)kl + swz(brow, ccol));
                __builtin_amdgcn_s_setprio(1);
                sacc[jf] = __builtin_amdgcn_mfma_f32_16x16x32_bf16(bh, qh[ks], sacc[jf], 0, 0, 0);
                sacc[jf] = __builtin_amdgcn_mfma_f32_16x16x32_bf16(bh, ql[ks], sacc[jf], 0, 0, 0);
                sacc[jf] = __builtin_amdgcn_mfma_f32_16x16x32_bf16(bl, qh[ks], sacc[jf], 0, 0, 0);
                __builtin_amdgcn_s_setprio(0);
            }
        }

        // ---- in-register online softmax (lane owns full row of 16 keys) ----
        float mloc = sacc[0][0];
        #pragma unroll
        for (int jf = 0; jf < 4; ++jf)
            #pragma unroll
            for (int r = 0; r < 4; ++r) mloc = fmaxf(mloc, sacc[jf][r]);
        mloc = fmaxf(mloc, __shfl_xor(mloc, 16));
        mloc = fmaxf(mloc, __shfl_xor(mloc, 32));
        float mnew  = fmaxf(m_, mloc);
        float alpha = __expf(m_ - mnew);
        m_ = mnew;

        float ssum = 0.f;
        #pragma unroll
        for (int jf = 0; jf < 4; ++jf) {
            float p0 = __expf(sacc[jf][0] - mnew);
            float p1 = __expf(sacc[jf][1] - mnew);
            float p2 = __expf(sacc[jf][2] - mnew);
            float p3 = __expf(sacc[jf][3] - mnew);
            ssum += (p0 + p1) + (p2 + p3);
            unsigned h01, h23;
            asm("v_cvt_pk_bf16_f32 %0, %1, %2" : "=v"(h01) : "v"(p0), "v"(p1));
            asm("v_cvt_pk_bf16_f32 %0, %1, %2" : "=v"(h23) : "v"(p2), "v"(p3));
            float q0 = p0 - __uint_as_float(h01 << 16);
            float q1 = p1 - __uint_as_float(h01 & 0xffff0000u);
            float q2 = p2 - __uint_as_float(h23 << 16);
            float q3 = p3 - __uint_as_float(h23 & 0xffff0000u);
            unsigned g01, g23;
            asm("v_cvt_pk_bf16_f32 %0, %1, %2" : "=v"(g01) : "v"(q0), "v"(q1));
            asm("v_cvt_pk_bf16_f32 %0, %1, %2" : "=v"(g23) : "v"(q2), "v"(q3));
            // key pair (16jf+4g+2t, +1) -> byte col (32jf+8g+4t)
            int c0 = swz(qrow_l, 32 * jf + 8 * g + 0);
            int c1 = swz(qrow_l, 32 * jf + 8 * g + 4);
            *reinterpret_cast<unsigned*>((char*)sPh + c0) = h01;
            *reinterpret_cast<unsigned*>((char*)sPh + c1) = h23;
            *reinterpret_cast<unsigned*>((char*)sPl + c0) = g01;
            *reinterpret_cast<unsigned*>((char*)sPl + c1) = g23;
        }
        ssum += __shfl_xor(ssum, 16);
        ssum += __shfl_xor(ssum, 32);
        l_ = l_ * alpha + ssum;

        // rescale O (rows q = g*4+r need alpha from lane fr = g*4+r)
        #pragma unroll
        for (int r = 0; r < 4; ++r) {
            float ar = __shfl(alpha, 16 * g + g * 4 + r);
            #pragma unroll
            for (int df = 0; df < 4; ++df) oacc[df][r] *= ar;
        }

        asm volatile("s_waitcnt lgkmcnt(0)" ::: "memory");
        __builtin_amdgcn_sched_barrier(0);

        // ---- O += P V (3-pass split) ----
        #pragma unroll
        for (int ks = 0; ks < 2; ++ks) {
            int kcol = (ks * 32 + g * 8) * 2;
            short8 pah = *reinterpret_cast<const short8*>((char*)sPh + swz(qrow_l, kcol));
            short8 pal = *reinterpret_cast<const short8*>((char*)sPl + swz(qrow_l, kcol));
            #pragma unroll
            for (int df = 0; df < 4; ++df) {
                int vrow = df * 16 + fr;
                short8 vbh = *reinterpret_cast<const short8*>((const char*)vh + swz(vrow, kcol));
                short8 vbl = *reinterpret_cast<const short8*>((const char*)vl + swz(vrow, kcol));
                __builtin_amdgcn_s_setprio(1);
                oacc[df] = __builtin_amdgcn_mfma_f32_16x16x32_bf16(pah, vbh, oacc[df], 0, 0, 0);
                oacc[df] = __builtin_amdgcn_mfma_f32_16x16x32_bf16(pah, vbl, oacc[df], 0, 0, 0);
                oacc[df] = __builtin_amdgcn_mfma_f32_16x16x32_bf16(pal, vbh, oacc[df], 0, 0, 0);
                __builtin_amdgcn_s_setprio(0);
            }
        }
        cur ^= 1;
    }

    // ---- epilogue: O/l -> hi/lo bf16 (1/l fetched per D-row) ----
    float linv = 1.f / l_;
    #pragma unroll
    for (int r = 0; r < 4; ++r) {
        float lr = __shfl(linv, 16 * g + g * 4 + r);
        int row = qt * 64 + w * 16 + g * 4 + r;
        #pragma unroll
        for (int df = 0; df < 4; ++df) {
            float v = oacc[df][r] * lr;
            unsigned short hh = f2bf(v);
            size_t o = ((size_t)b * SEQ + row) * DM + h * 64 + df * 16 + fr;
            out_hi[o] = hh;
            out_lo[o] = f2bf(v - bf2f(hh));
        }
    }
    #undef STAGE_TILE
}

extern "C" void kernel_launch(void* const* d_in, const int* in_sizes, int n_in,
                              void* d_out, int out_size, void* d_ws, size_t ws_size,
                              hipStream_t stream) {
    const float* x     = (const float*)d_in[0];
    const float* w_qkv = (const float*)d_in[1];
    const float* w_out = (const float*)d_in[2];
    const float* b_out = (const float*)d_in[3];
    float* out = (float*)d_out;

    const int M = BATCH * SEQ;                    // 8192

    char* ws = (char*)d_ws;
    unsigned short* qkv_h = (unsigned short*)ws;                         ws += (size_t)M * 3072 * 2;
    unsigned short* qkv_l = (unsigned short*)ws;                         ws += (size_t)M * 3072 * 2;
    unsigned short* x_hi  = (unsigned short*)ws;                         ws += (size_t)M * DM * 2;
    unsigned short* x_lo  = (unsigned short*)ws;                         ws += (size_t)M * DM * 2;
    unsigned short* wqT_h = (unsigned short*)ws;                         ws += (size_t)3072 * DM * 2;
    unsigned short* wqT_l = (unsigned short*)ws;                         ws += (size_t)3072 * DM * 2;
    unsigned short* woT_h = (unsigned short*)ws;                         ws += (size_t)DM * DM * 2;
    unsigned short* woT_l = (unsigned short*)ws;                         ws += (size_t)DM * DM * 2;
    unsigned short* at_hi = (unsigned short*)ws;                         ws += (size_t)M * DM * 2;
    unsigned short* at_lo = (unsigned short*)ws;

    unsigned short* Vth = x_hi;   // alias: dead after GEMM1
    unsigned short* Vtl = x_lo;

    dim3 blk(256);

    split_hl<<<dim3((M * DM / 4 + 255) / 256), blk, 0, stream>>>(x, x_hi, x_lo, M * DM / 4);
    splitT_hl<<<dim3(3072 / 32, DM / 32), blk, 0, stream>>>(w_qkv, wqT_h, wqT_l, DM, 3 * DM);
    splitT_hl<<<dim3(DM / 32, DM / 32), blk, 0, stream>>>(w_out, woT_h, woT_l, DM, DM);

    gemm_bt_3p_t<1><<<dim3(M / 128, 3 * DM / 128), blk, 0, stream>>>(
        x_hi, x_lo, wqT_h, wqT_l, nullptr, nullptr, qkv_h, qkv_l, M, 3 * DM, DM);

    vt_prep_bf<<<dim3(SEQ / 32, DH / 32, BATCH * NH), blk, 0, stream>>>(
        qkv_h, qkv_l, Vth, Vtl);

    flash_attn_mfma<<<dim3(SEQ / 64, NH, BATCH), blk, 0, stream>>>(
        qkv_h, qkv_l, Vth, Vtl, at_hi, at_lo);

    gemm_bt_3p_t<0><<<dim3(M / 128, DM / 128), blk, 0, stream>>>(
        at_hi, at_lo, woT_h, woT_l, b_out, out, nullptr, nullptr, M, DM, DM);
}

// Round 6
// 483.927 us; speedup vs baseline: 4.5960x; 1.1168x over previous
//
#include <hip/hip_runtime.h>
#include <math.h>

#define DM   1024
#define NH   16
#define DH   64
#define SEQ  2048
#define BATCH 4

typedef __attribute__((ext_vector_type(8))) short  short8;
typedef __attribute__((ext_vector_type(4))) float  f32x4;

// ---- fp32 -> bf16 hi/lo split helpers (RNE) -------------------------------
static __device__ __forceinline__ unsigned short f2bf(float f) {
    unsigned u = __float_as_uint(f);
    unsigned r = (u + 0x7fffu + ((u >> 16) & 1u)) >> 16;
    return (unsigned short)r;
}
static __device__ __forceinline__ float bf2f(unsigned short h) {
    return __uint_as_float(((unsigned)h) << 16);
}

// swizzled byte offset inside a [rows][128B] LDS tile (T2-style, G4 rule)
static __device__ __forceinline__ int swz(int row, int cbyte) {
    return row * 128 + (cbyte ^ ((row & 7) << 4));
}

#define GLD(gp, lp) __builtin_amdgcn_global_load_lds( \
    (const __attribute__((address_space(1))) void*)(gp), \
    (__attribute__((address_space(3))) void*)(lp), 16, 0, 0)

// ---- prep: elementwise split fp32 -> (hi, lo) bf16, same layout -----------
__global__ __launch_bounds__(256) void split_hl(
    const float* __restrict__ in, unsigned short* __restrict__ hi,
    unsigned short* __restrict__ lo, int n4)
{
    int i = blockIdx.x * 256 + threadIdx.x;
    if (i >= n4) return;
    float4 v = reinterpret_cast<const float4*>(in)[i];
    ushort4 h, L;
    h.x = f2bf(v.x); L.x = f2bf(v.x - bf2f(h.x));
    h.y = f2bf(v.y); L.y = f2bf(v.y - bf2f(h.y));
    h.z = f2bf(v.z); L.z = f2bf(v.z - bf2f(h.z));
    h.w = f2bf(v.w); L.w = f2bf(v.w - bf2f(h.w));
    reinterpret_cast<ushort4*>(hi)[i] = h;
    reinterpret_cast<ushort4*>(lo)[i] = L;
}

// ---- prep: split + transpose: in[K][N] fp32 -> hiT/loT[N][K] bf16 ---------
__global__ __launch_bounds__(256) void splitT_hl(
    const float* __restrict__ in, unsigned short* __restrict__ hiT,
    unsigned short* __restrict__ loT, int K, int N)
{
    __shared__ float t[32][33];
    const int n0 = blockIdx.x * 32, k0 = blockIdx.y * 32;
    const int tx = threadIdx.x & 31, ty = threadIdx.x >> 5;
    #pragma unroll
    for (int r = 0; r < 32; r += 8)
        t[ty + r][tx] = in[(size_t)(k0 + ty + r) * N + n0 + tx];
    __syncthreads();
    #pragma unroll
    for (int r = 0; r < 32; r += 8) {
        float v = t[tx][ty + r];
        unsigned short h = f2bf(v);
        size_t o = (size_t)(n0 + ty + r) * K + k0 + tx;
        hiT[o] = h;
        loT[o] = f2bf(v - bf2f(h));
    }
}

// ---- prep: V transpose (bf16 hi/lo): qkv V-section -> Vt[bh][d][seq] ------
__global__ __launch_bounds__(256) void vt_prep_bf(
    const unsigned short* __restrict__ qh, const unsigned short* __restrict__ ql,
    unsigned short* __restrict__ Vth, unsigned short* __restrict__ Vtl)
{
    __shared__ unsigned short th[32][34], tl[32][34];
    const int s0 = blockIdx.x * 32, d0 = blockIdx.y * 32, bh = blockIdx.z;
    const int b = bh >> 4, h = bh & 15;
    const int tx = threadIdx.x & 31, ty = threadIdx.x >> 5;
    #pragma unroll
    for (int r = 0; r < 32; r += 8) {
        size_t src = ((size_t)b * SEQ + s0 + ty + r) * 3072 + 2048 + h * 64 + d0 + tx;
        th[ty + r][tx] = qh[src];
        tl[ty + r][tx] = ql[src];
    }
    __syncthreads();
    #pragma unroll
    for (int r = 0; r < 32; r += 8) {
        size_t o = ((size_t)bh * 64 + d0 + ty + r) * SEQ + s0 + tx;
        Vth[o] = th[tx][ty + r];
        Vtl[o] = tl[tx][ty + r];
    }
}

// ---- split-bf16 3-pass MFMA GEMM core -------------------------------------
// MODE 0: C fp32 + bias.  MODE 1: C -> hi/lo bf16, cols<1024 scaled by 0.125.
template <int MODE>
__global__ __launch_bounds__(256) void gemm_bt_3p_t(
    const unsigned short* __restrict__ Ah, const unsigned short* __restrict__ Al,
    const unsigned short* __restrict__ Bh, const unsigned short* __restrict__ Bl,
    const float* __restrict__ bias, float* __restrict__ C,
    unsigned short* __restrict__ Ch, unsigned short* __restrict__ Cl,
    int M, int N, int K)
{
    __shared__ __align__(16) unsigned short sAh[128 * 32];
    __shared__ __align__(16) unsigned short sAl[128 * 32];
    __shared__ __align__(16) unsigned short sBh[128 * 32];
    __shared__ __align__(16) unsigned short sBl[128 * 32];

    const int tid = threadIdx.x;
    const int l = tid & 63, w = tid >> 6;
    const int wr = w >> 1, wc = w & 1;
    const int bm = blockIdx.x * 128, bn = blockIdx.y * 128;

    const int srow = w * 32 + (l >> 2);
    const int scol = (l & 3) * 8;
    const size_t a0 = (size_t)(bm + srow) * K + scol;
    const size_t a1 = (size_t)(bm + srow + 16) * K + scol;
    const size_t b0 = (size_t)(bn + srow) * K + scol;
    const size_t b1 = (size_t)(bn + srow + 16) * K + scol;

    const int fr = l & 15;
    const int fk = (l >> 4) * 8;

    f32x4 acc[4][4];
    #pragma unroll
    for (int i = 0; i < 4; ++i)
        #pragma unroll
        for (int j = 0; j < 4; ++j)
            acc[i][j] = (f32x4){0.f, 0.f, 0.f, 0.f};

    for (int k0 = 0; k0 < K; k0 += 32) {
        __syncthreads();
        GLD(Ah + a0 + k0, sAh + w * 1024);
        GLD(Ah + a1 + k0, sAh + w * 1024 + 512);
        GLD(Al + a0 + k0, sAl + w * 1024);
        GLD(Al + a1 + k0, sAl + w * 1024 + 512);
        GLD(Bh + b0 + k0, sBh + w * 1024);
        GLD(Bh + b1 + k0, sBh + w * 1024 + 512);
        GLD(Bl + b0 + k0, sBl + w * 1024);
        GLD(Bl + b1 + k0, sBl + w * 1024 + 512);
        __syncthreads();

        short8 vah[4], val[4], vbh[4], vbl[4];
        #pragma unroll
        for (int i = 0; i < 4; ++i) {
            int ar = (wr * 64 + i * 16 + fr) * 32 + fk;
            int br = (wc * 64 + i * 16 + fr) * 32 + fk;
            vah[i] = *reinterpret_cast<const short8*>(&sAh[ar]);
            val[i] = *reinterpret_cast<const short8*>(&sAl[ar]);
            vbh[i] = *reinterpret_cast<const short8*>(&sBh[br]);
            vbl[i] = *reinterpret_cast<const short8*>(&sBl[br]);
        }
        __builtin_amdgcn_s_setprio(1);
        #pragma unroll
        for (int i = 0; i < 4; ++i)
            #pragma unroll
            for (int j = 0; j < 4; ++j) {
                acc[i][j] = __builtin_amdgcn_mfma_f32_16x16x32_bf16(vah[i], vbh[j], acc[i][j], 0, 0, 0);
                acc[i][j] = __builtin_amdgcn_mfma_f32_16x16x32_bf16(vah[i], vbl[j], acc[i][j], 0, 0, 0);
                acc[i][j] = __builtin_amdgcn_mfma_f32_16x16x32_bf16(val[i], vbh[j], acc[i][j], 0, 0, 0);
            }
        __builtin_amdgcn_s_setprio(0);
    }

    #pragma unroll
    for (int i = 0; i < 4; ++i) {
        #pragma unroll
        for (int j = 0; j < 4; ++j) {
            int row = bm + wr * 64 + i * 16 + (l >> 4) * 4;
            int col = bn + wc * 64 + j * 16 + fr;
            if (MODE == 0) {
                float bb = bias ? bias[col] : 0.f;
                #pragma unroll
                for (int r = 0; r < 4; ++r)
                    C[(size_t)(row + r) * N + col] = acc[i][j][r] + bb;
            } else {
                float sc = (col < 1024) ? 0.125f : 1.0f;
                #pragma unroll
                for (int r = 0; r < 4; ++r) {
                    float v = acc[i][j][r] * sc;
                    unsigned short hh = f2bf(v);
                    size_t o = (size_t)(row + r) * N + col;
                    Ch[o] = hh;
                    Cl[o] = f2bf(v - bf2f(hh));
                }
            }
        }
    }
}

// ---- MFMA flash attention: QBLK=128 (32 q-rows/wave), swapped QK^T --------
// LDS: sK dbuf 32K + sV single 16K + sP 32K = 80KB -> 2 blocks/CU.
__global__ __launch_bounds__(256) void flash_attn_mfma(
    const unsigned short* __restrict__ QKh, const unsigned short* __restrict__ QKl,
    const unsigned short* __restrict__ Vth, const unsigned short* __restrict__ Vtl,
    unsigned short* __restrict__ out_hi, unsigned short* __restrict__ out_lo)
{
    __shared__ __align__(16) unsigned short sK[2][2][64 * 64];  // [buf][hi/lo]
    __shared__ __align__(16) unsigned short sVh[64 * 64], sVl[64 * 64];
    __shared__ __align__(16) unsigned short sPh[128 * 64], sPl[128 * 64];

    const int qt = blockIdx.x, h = blockIdx.y, b = blockIdx.z;
    const int tid = threadIdx.x;
    const int l = tid & 63, w = tid >> 6;
    const int fr = l & 15, g = l >> 4;

    const size_t kgbase = (size_t)b * SEQ * 3072 + 1024 + h * 64;
    const size_t vtb    = ((size_t)(b * NH + h)) * 64 * SEQ;

    int sg_r[2], sg_c[2];
    #pragma unroll
    for (int i2 = 0; i2 < 2; ++i2) {
        int gi = (w * 2 + i2) * 64 + l;
        sg_r[i2] = gi >> 3;
        sg_c[i2] = (gi & 7) ^ (sg_r[i2] & 7);    // inverse-swizzled source chunk
    }

    #define STAGE_K(cbuf, kt_) do {                                            \
        _Pragma("unroll")                                                      \
        for (int i2 = 0; i2 < 2; ++i2) {                                       \
            int i = w * 2 + i2;                                                \
            size_t gk = kgbase + (size_t)((kt_) * 64 + sg_r[i2]) * 3072 + sg_c[i2] * 8; \
            GLD(QKh + gk, (char*)&sK[cbuf][0][0] + i * 1024);                  \
            GLD(QKl + gk, (char*)&sK[cbuf][1][0] + i * 1024);                  \
        }                                                                      \
    } while (0)

    #define STAGE_V(kt_) do {                                                  \
        _Pragma("unroll")                                                      \
        for (int i2 = 0; i2 < 2; ++i2) {                                       \
            int i = w * 2 + i2;                                                \
            size_t gv = vtb + (size_t)sg_r[i2] * SEQ + (size_t)(kt_) * 64 + sg_c[i2] * 8; \
            GLD(Vth + gv, (char*)sVh + i * 1024);                              \
            GLD(Vtl + gv, (char*)sVl + i * 1024);                              \
        }                                                                      \
    } while (0)

    // ---- Q fragments direct to registers (pre-scaled in GEMM1 epilogue) ----
    short8 qh[2][2], ql[2][2];           // [sub][ks]
    #pragma unroll
    for (int sub = 0; sub < 2; ++sub) {
        const int qrow = qt * 128 + w * 32 + sub * 16 + fr;
        const size_t qb = ((size_t)b * SEQ + qrow) * 3072 + h * 64;
        #pragma unroll
        for (int ks = 0; ks < 2; ++ks) {
            qh[sub][ks] = *reinterpret_cast<const short8*>(QKh + qb + ks * 32 + g * 8);
            ql[sub][ks] = *reinterpret_cast<const short8*>(QKl + qb + ks * 32 + g * 8);
        }
    }

    float m_[2] = {-1e30f, -1e30f}, l_[2] = {0.f, 0.f};
    f32x4 oacc[2][4];
    #pragma unroll
    for (int sub = 0; sub < 2; ++sub)
        #pragma unroll
        for (int d = 0; d < 4; ++d) oacc[sub][d] = (f32x4){0.f, 0.f, 0.f, 0.f};

    STAGE_K(0, 0);
    int cur = 0;

    for (int kt = 0; kt < SEQ / 64; ++kt) {
        __syncthreads();                  // (A) K[cur] ready; sV free; sP free
        STAGE_V(kt);
        if (kt + 1 < SEQ / 64) STAGE_K(cur ^ 1, kt + 1);

        const unsigned short* kh = &sK[cur][0][0];
        const unsigned short* kl = &sK[cur][1][0];

        // ---- S^T = K Q^T (swapped; 3-pass; one K-frag feeds both subs) ----
        f32x4 sacc[2][4];
        #pragma unroll
        for (int sub = 0; sub < 2; ++sub)
            #pragma unroll
            for (int jf = 0; jf < 4; ++jf) sacc[sub][jf] = (f32x4){0.f, 0.f, 0.f, 0.f};
        #pragma unroll
        for (int ks = 0; ks < 2; ++ks) {
            int ccol = (ks * 32 + g * 8) * 2;
            #pragma unroll
            for (int jf = 0; jf < 4; ++jf) {
                int brow = jf * 16 + fr;
                short8 bh = *reinterpret_cast<const short8*>((const char*)kh + swz(brow, ccol));
                short8 bl = *reinterpret_cast<const short8*>((const char*)kl + swz(brow, ccol));
                __builtin_amdgcn_s_setprio(1);
                #pragma unroll
                for (int sub = 0; sub < 2; ++sub) {
                    sacc[sub][jf] = __builtin_amdgcn_mfma_f32_16x16x32_bf16(bh, qh[sub][ks], sacc[sub][jf], 0, 0, 0);
                    sacc[sub][jf] = __builtin_amdgcn_mfma_f32_16x16x32_bf16(bh, ql[sub][ks], sacc[sub][jf], 0, 0, 0);
                    sacc[sub][jf] = __builtin_amdgcn_mfma_f32_16x16x32_bf16(bl, qh[sub][ks], sacc[sub][jf], 0, 0, 0);
                }
                __builtin_amdgcn_s_setprio(0);
            }
        }

        // ---- in-register online softmax (lane owns rows w*32+sub*16+fr) ----
        #pragma unroll
        for (int sub = 0; sub < 2; ++sub) {
            float mloc = sacc[sub][0][0];
            #pragma unroll
            for (int jf = 0; jf < 4; ++jf)
                #pragma unroll
                for (int r = 0; r < 4; ++r) mloc = fmaxf(mloc, sacc[sub][jf][r]);
            mloc = fmaxf(mloc, __shfl_xor(mloc, 16));
            mloc = fmaxf(mloc, __shfl_xor(mloc, 32));
            float mnew  = fmaxf(m_[sub], mloc);
            float alpha = __expf(m_[sub] - mnew);
            m_[sub] = mnew;

            const int prow = w * 32 + sub * 16 + fr;
            float ssum = 0.f;
            #pragma unroll
            for (int jf = 0; jf < 4; ++jf) {
                float p0 = __expf(sacc[sub][jf][0] - mnew);
                float p1 = __expf(sacc[sub][jf][1] - mnew);
                float p2 = __expf(sacc[sub][jf][2] - mnew);
                float p3 = __expf(sacc[sub][jf][3] - mnew);
                ssum += (p0 + p1) + (p2 + p3);
                unsigned h01, h23;
                asm("v_cvt_pk_bf16_f32 %0, %1, %2" : "=v"(h01) : "v"(p0), "v"(p1));
                asm("v_cvt_pk_bf16_f32 %0, %1, %2" : "=v"(h23) : "v"(p2), "v"(p3));
                float q0 = p0 - __uint_as_float(h01 << 16);
                float q1 = p1 - __uint_as_float(h01 & 0xffff0000u);
                float q2 = p2 - __uint_as_float(h23 << 16);
                float q3 = p3 - __uint_as_float(h23 & 0xffff0000u);
                unsigned g01, g23;
                asm("v_cvt_pk_bf16_f32 %0, %1, %2" : "=v"(g01) : "v"(q0), "v"(q1));
                asm("v_cvt_pk_bf16_f32 %0, %1, %2" : "=v"(g23) : "v"(q2), "v"(q3));
                int c0 = swz(prow, 32 * jf + 8 * g);
                uint2 ph; ph.x = h01; ph.y = h23;
                uint2 pl; pl.x = g01; pl.y = g23;
                *reinterpret_cast<uint2*>((char*)sPh + c0) = ph;   // ds_write_b64
                *reinterpret_cast<uint2*>((char*)sPl + c0) = pl;
            }
            ssum += __shfl_xor(ssum, 16);
            ssum += __shfl_xor(ssum, 32);
            l_[sub] = l_[sub] * alpha + ssum;

            #pragma unroll
            for (int r = 0; r < 4; ++r) {
                float ar = __shfl(alpha, 16 * g + g * 4 + r);
                #pragma unroll
                for (int df = 0; df < 4; ++df) oacc[sub][df][r] *= ar;
            }
        }

        __syncthreads();                  // (B) V(kt) arrived; P visible

        // ---- O += P V (3-pass; one V-frag feeds both subs) ----
        #pragma unroll
        for (int ks = 0; ks < 2; ++ks) {
            int kcol = (ks * 32 + g * 8) * 2;
            short8 pah[2], pal[2];
            #pragma unroll
            for (int sub = 0; sub < 2; ++sub) {
                int prow = w * 32 + sub * 16 + fr;
                pah[sub] = *reinterpret_cast<const short8*>((char*)sPh + swz(prow, kcol));
                pal[sub] = *reinterpret_cast<const short8*>((char*)sPl + swz(prow, kcol));
            }
            #pragma unroll
            for (int df = 0; df < 4; ++df) {
                int vrow = df * 16 + fr;
                short8 vbh = *reinterpret_cast<const short8*>((char*)sVh + swz(vrow, kcol));
                short8 vbl = *reinterpret_cast<const short8*>((char*)sVl + swz(vrow, kcol));
                __builtin_amdgcn_s_setprio(1);
                #pragma unroll
                for (int sub = 0; sub < 2; ++sub) {
                    oacc[sub][df] = __builtin_amdgcn_mfma_f32_16x16x32_bf16(pah[sub], vbh, oacc[sub][df], 0, 0, 0);
                    oacc[sub][df] = __builtin_amdgcn_mfma_f32_16x16x32_bf16(pah[sub], vbl, oacc[sub][df], 0, 0, 0);
                    oacc[sub][df] = __builtin_amdgcn_mfma_f32_16x16x32_bf16(pal[sub], vbh, oacc[sub][df], 0, 0, 0);
                }
                __builtin_amdgcn_s_setprio(0);
            }
        }
        cur ^= 1;
    }

    // ---- epilogue: O/l -> hi/lo bf16 ----
    #pragma unroll
    for (int sub = 0; sub < 2; ++sub) {
        float linv = 1.f / l_[sub];
        #pragma unroll
        for (int r = 0; r < 4; ++r) {
            float lr = __shfl(linv, 16 * g + g * 4 + r);
            int row = qt * 128 + w * 32 + sub * 16 + g * 4 + r;
            #pragma unroll
            for (int df = 0; df < 4; ++df) {
                float v = oacc[sub][df][r] * lr;
                unsigned short hh = f2bf(v);
                size_t o = ((size_t)b * SEQ + row) * DM + h * 64 + df * 16 + fr;
                out_hi[o] = hh;
                out_lo[o] = f2bf(v - bf2f(hh));
            }
        }
    }
    #undef STAGE_K
    #undef STAGE_V
}

extern "C" void kernel_launch(void* const* d_in, const int* in_sizes, int n_in,
                              void* d_out, int out_size, void* d_ws, size_t ws_size,
                              hipStream_t stream) {
    const float* x     = (const float*)d_in[0];
    const float* w_qkv = (const float*)d_in[1];
    const float* w_out = (const float*)d_in[2];
    const float* b_out = (const float*)d_in[3];
    float* out = (float*)d_out;

    const int M = BATCH * SEQ;                    // 8192

    char* ws = (char*)d_ws;
    unsigned short* qkv_h = (unsigned short*)ws;                         ws += (size_t)M * 3072 * 2;
    unsigned short* qkv_l = (unsigned short*)ws;                         ws += (size_t)M * 3072 * 2;
    unsigned short* x_hi  = (unsigned short*)ws;                         ws += (size_t)M * DM * 2;
    unsigned short* x_lo  = (unsigned short*)ws;                         ws += (size_t)M * DM * 2;
    unsigned short* wqT_h = (unsigned short*)ws;                         ws += (size_t)3072 * DM * 2;
    unsigned short* wqT_l = (unsigned short*)ws;                         ws += (size_t)3072 * DM * 2;
    unsigned short* woT_h = (unsigned short*)ws;                         ws += (size_t)DM * DM * 2;
    unsigned short* woT_l = (unsigned short*)ws;                         ws += (size_t)DM * DM * 2;
    unsigned short* at_hi = (unsigned short*)ws;                         ws += (size_t)M * DM * 2;
    unsigned short* at_lo = (unsigned short*)ws;

    unsigned short* Vth = x_hi;   // alias: dead after GEMM1
    unsigned short* Vtl = x_lo;

    dim3 blk(256);

    split_hl<<<dim3((M * DM / 4 + 255) / 256), blk, 0, stream>>>(x, x_hi, x_lo, M * DM / 4);
    splitT_hl<<<dim3(3072 / 32, DM / 32), blk, 0, stream>>>(w_qkv, wqT_h, wqT_l, DM, 3 * DM);
    splitT_hl<<<dim3(DM / 32, DM / 32), blk, 0, stream>>>(w_out, woT_h, woT_l, DM, DM);

    gemm_bt_3p_t<1><<<dim3(M / 128, 3 * DM / 128), blk, 0, stream>>>(
        x_hi, x_lo, wqT_h, wqT_l, nullptr, nullptr, qkv_h, qkv_l, M, 3 * DM, DM);

    vt_prep_bf<<<dim3(SEQ / 32, DH / 32, BATCH * NH), blk, 0, stream>>>(
        qkv_h, qkv_l, Vth, Vtl);

    flash_attn_mfma<<<dim3(SEQ / 128, NH, BATCH), blk, 0, stream>>>(
        qkv_h, qkv_l, Vth, Vtl, at_hi, at_lo);

    gemm_bt_3p_t<0><<<dim3(M / 128, DM / 128), blk, 0, stream>>>(
        at_hi, at_lo, woT_h, woT_l, b_out, out, nullptr, nullptr, M, DM, DM);
}